// Round 4
// baseline (547.147 us; speedup 1.0000x reference)
//
#include <hip/hip_runtime.h>
#include <hip/hip_cooperative_groups.h>
#include <math.h>

namespace cg = cooperative_groups;

// ---------------------------------------------------------------------------
// AttentionBlock: GN(4,256) -> QKV 1x1 conv -> 2-head attn (N=1024, hd=128)
// -> proj -> +residual.  B=16, C=256, H=W=32 (N=1024), fp32 in/out.
// R8: cooperative fused kernel (512x256, 4 phases, grid.sync) with LDS fixed
// to EXACTLY 64 KiB (R7 failed: 65568 B > sharedMemPerBlock => silent launch
// failure, out==0, absmax 5.0 = max|ref|). gs8 now lives inside the overlay.
// Fallback: if cooperative launch errors, run the verified R6 4-kernel path.
// ---------------------------------------------------------------------------

typedef __attribute__((ext_vector_type(8))) short bf16x8;   // 8 bf16 = 4 VGPRs
typedef __attribute__((ext_vector_type(4))) float f32x4;

__device__ __forceinline__ unsigned short f2bf(float f) {   // RNE-ish
    union { float f; unsigned u; } v; v.f = f;
    return (unsigned short)((v.u + 0x7FFFu + ((v.u >> 16) & 1u)) >> 16);
}
__device__ __forceinline__ unsigned bfbits(float f) {       // +half (round up)
    union { float f; unsigned u; } v; v.f = f;
    return v.u + 0x8000u;
}
// pack two floats -> (bf(a) | bf(b)<<16) in 3 VALU ops
__device__ __forceinline__ unsigned packbf(float a, float b) {
    return __builtin_amdgcn_perm(bfbits(b), bfbits(a), 0x07060302u);
}

__device__ __forceinline__ void gload_lds16(const void* g, void* l) {
    __builtin_amdgcn_global_load_lds(
        (const __attribute__((address_space(1))) unsigned int*)g,
        (__attribute__((address_space(3))) unsigned int*)l, 16, 0, 0);
}

// ======================= FUSED cooperative kernel ==========================
__global__ __launch_bounds__(256, 2) void fused_all(
    const float* __restrict__ x,
    const float* __restrict__ gnw,
    const float* __restrict__ gnb,
    const float* __restrict__ wq,
    const float* __restrict__ wk,
    const float* __restrict__ wv,
    const float* __restrict__ wp,
    float* __restrict__ acc,
    unsigned short* __restrict__ wqb,
    unsigned short* __restrict__ wkb,
    unsigned short* __restrict__ wvb,
    unsigned short* __restrict__ wpb,
    unsigned short* __restrict__ qt,
    unsigned short* __restrict__ kt,
    unsigned short* __restrict__ vv,
    unsigned short* __restrict__ ot,
    float* __restrict__ out)
{
    cg::grid_group grid = cg::this_grid();
    int bid = blockIdx.x;
    int tid = threadIdx.x;
    __shared__ __align__(16) unsigned short smem[32768];   // EXACTLY 64 KiB

    // ================= phase 0: weights->bf16 + GN partial stats ==========
    {
        int t = tid;
        if (t < 128) {                       // 512 weight floats per block
            int idx = bid * 512 + t * 4;
            int which = idx >> 16, i = idx & 65535;
            const float* src = (which == 0) ? wq : (which == 1) ? wk : (which == 2) ? wv : wp;
            unsigned short* dst = (which == 0) ? wqb : (which == 1) ? wkb : (which == 2) ? wvb : wpb;
            // fold softmax scale 512^-0.5 AND log2(e) into wq (softmax uses exp2)
            float scl = (which == 0) ? (0.044194173824159216f * 1.4426950408889634f) : 1.0f;
            float4 v = *(const float4*)(src + i);
            ushort4 o;
            o.x = f2bf(v.x * scl); o.y = f2bf(v.y * scl);
            o.z = f2bf(v.z * scl); o.w = f2bf(v.w * scl);
            *(ushort4*)(dst + i) = o;
        }
        // GN partial sums: block covers 8192 floats of x
        int bg = bid >> 3, ch = bid & 7;
        const float4* xp = (const float4*)(x + (size_t)bg * 65536 + ch * 8192);
        float s = 0.f, s2 = 0.f;
#pragma unroll
        for (int i = 0; i < 8; i++) {
            float4 v = xp[t + i * 256];
            s  += v.x + v.y + v.z + v.w;
            s2 += v.x * v.x + v.y * v.y + v.z * v.z + v.w * v.w;
        }
        for (int m = 1; m < 64; m <<= 1) { s += __shfl_xor(s, m); s2 += __shfl_xor(s2, m); }
        float* ls = (float*)smem;
        int w = t >> 6, lane = t & 63;
        if (lane == 0) { ls[w] = s; ls[4 + w] = s2; }
        __syncthreads();
        if (t == 0) {
            acc[bg * 16 + ch * 2]     = ls[0] + ls[1] + ls[2] + ls[3];
            acc[bg * 16 + ch * 2 + 1] = ls[4] + ls[5] + ls[6] + ls[7];
        }
    }
    __threadfence();
    grid.sync();
    __threadfence();   // acquire side: invalidate after ALL writers flushed

    // ================= phase 1: GN-normalize + QKV GEMM ====================
    {
        int b = bid >> 5, half = (bid >> 4) & 1, nx = bid & 15;
        int n0 = nx * 64;
        int t = tid, w = t >> 6, lane = t & 63, quad = lane >> 4, c4 = lane & 15;
        unsigned short* xl = smem;                    // p1: [64][264]; p2: Q-et@0, K-et@8704
        unsigned short* ebuf = smem + 17408;          // V-et2 [128][72], ends @26624
        float* gsf = (float*)(smem + 26624);          // 8 floats @ byte 53248
        if (t < 4) {
            float s0 = 0.f, s1 = 0.f;
#pragma unroll
            for (int p = 0; p < 8; p++) {
                s0 += acc[(b * 4 + t) * 16 + p * 2];
                s1 += acc[(b * 4 + t) * 16 + p * 2 + 1];
            }
            float mean = s0 * (1.f / 65536.f);
            float var = s1 * (1.f / 65536.f) - mean * mean;
            gsf[2 * t] = mean;
            gsf[2 * t + 1] = rsqrtf(var + 1e-5f);
        }
        __syncthreads();
        // ---- load + normalize x-tile -> xl [n 64][c pitch 264]
        {
            int col = t & 15, crow = t >> 4;
#pragma unroll
            for (int p = 0; p < 16; p++) {
                int c = p * 16 + crow;
                int g = c >> 6;
                float sc = gsf[g * 2 + 1] * gnw[c];
                float bs = gnb[c] - gsf[g * 2] * sc;
                float4 v = *(const float4*)(x + ((size_t)b * 256 + c) * 1024 + n0 + col * 4);
                int nl = col * 4;
                xl[(nl + 0) * 264 + c] = (unsigned short)(bfbits(fmaf(v.x, sc, bs)) >> 16);
                xl[(nl + 1) * 264 + c] = (unsigned short)(bfbits(fmaf(v.y, sc, bs)) >> 16);
                xl[(nl + 2) * 264 + c] = (unsigned short)(bfbits(fmaf(v.z, sc, bs)) >> 16);
                xl[(nl + 3) * 264 + c] = (unsigned short)(bfbits(fmaf(v.w, sc, bs)) >> 16);
            }
        }
        __syncthreads();
        int wm = (w >> 1) * 64, wn = (w & 1) * 32;
        int mbase = half * 128 + wm;
        int bh = b * 2 + half;
        f32x4 aq[4][2] = {}, akk[4][2] = {}, av[4][2] = {};
#pragma unroll
        for (int k = 0; k < 256; k += 32) {
            bf16x8 bfr[2];
#pragma unroll
            for (int i = 0; i < 2; i++)
                bfr[i] = *(const bf16x8*)&xl[(wn + i * 16 + c4) * 264 + k + quad * 8];
#pragma unroll
            for (int mi = 0; mi < 4; mi++) {
                bf16x8 afq = *(const bf16x8*)(wqb + (mbase + mi * 16 + c4) * 256 + k + quad * 8);
                bf16x8 afk = *(const bf16x8*)(wkb + (mbase + mi * 16 + c4) * 256 + k + quad * 8);
                bf16x8 afv = *(const bf16x8*)(wvb + (mbase + mi * 16 + c4) * 256 + k + quad * 8);
#pragma unroll
                for (int ni = 0; ni < 2; ni++) {
                    aq[mi][ni]  = __builtin_amdgcn_mfma_f32_16x16x32_bf16(afq, bfr[ni], aq[mi][ni], 0, 0, 0);
                    akk[mi][ni] = __builtin_amdgcn_mfma_f32_16x16x32_bf16(afk, bfr[ni], akk[mi][ni], 0, 0, 0);
                    av[mi][ni]  = __builtin_amdgcn_mfma_f32_16x16x32_bf16(afv, bfr[ni], av[mi][ni], 0, 0, 0);
                }
            }
        }
        __syncthreads();   // xl reads done; reuse xl + ebuf for epilogue
#pragma unroll
        for (int mi = 0; mi < 4; mi++)
#pragma unroll
            for (int ni = 0; ni < 2; ni++) {
                int row = wn + ni * 16 + c4;          // i-local
                int col = wm + mi * 16 + quad * 4;    // ch
                uint2 uq, uk;
                uq.x = packbf(aq[mi][ni][0], aq[mi][ni][1]);
                uq.y = packbf(aq[mi][ni][2], aq[mi][ni][3]);
                uk.x = packbf(akk[mi][ni][0], akk[mi][ni][1]);
                uk.y = packbf(akk[mi][ni][2], akk[mi][ni][3]);
                *(uint2*)&xl[row * 136 + col] = uq;
                *(uint2*)&xl[8704 + row * 136 + col] = uk;
#pragma unroll
                for (int r = 0; r < 4; r++)
                    ebuf[(col + r) * 72 + row] = f2bf(av[mi][ni][r]);
            }
        __syncthreads();
#pragma unroll
        for (int p = 0; p < 4; p++) {
            int i = p * 16 + (t >> 4), off = (t & 15) * 8;
            *(bf16x8*)(qt + ((size_t)bh * 1024 + n0 + i) * 128 + off) =
                *(const bf16x8*)&xl[i * 136 + off];
            *(bf16x8*)(kt + ((size_t)bh * 1024 + n0 + i) * 128 + off) =
                *(const bf16x8*)&xl[8704 + i * 136 + off];
        }
#pragma unroll
        for (int p = 0; p < 4; p++) {
            int ch = p * 32 + (t >> 3), off = (t & 7) * 8;
            *(bf16x8*)(vv + ((size_t)bh * 128 + ch) * 1024 + n0 + off) =
                *(const bf16x8*)&ebuf[ch * 72 + off];
        }
    }
    __threadfence();
    grid.sync();
    __threadfence();

    // ================= phase 2: flash attention ============================
    {
        int L = bid;
        int xcd = L & 7, jj = L >> 3;
        int bh = (jj >> 4) * 8 + xcd;       // 4 bh per XCD
        int qb = jj & 15;
        int b = bh >> 1, h = bh & 1;
        int w = tid >> 6, lane = tid & 63;
        int quad = lane >> 4, c4 = lane & 15;
        unsigned short* klds = smem;             // [2][8192] shorts
        unsigned short* vlds = smem + 16384;     // [2][8192] shorts

        const unsigned short* qp = qt + (size_t)bh * 1024 * 128;
        const unsigned short* kp = kt + (size_t)bh * 1024 * 128;
        const unsigned short* vp = vv + (size_t)bh * 128 * 1024;
        int i0 = qb * 64 + w * 16;

        // Q B-frags (16 rows) kept in regs: i = i0 + c4, k = kk*32 + quad*8
        bf16x8 bq[4];
#pragma unroll
        for (int kk = 0; kk < 4; kk++)
            bq[kk] = *(const bf16x8*)(qp + (size_t)(i0 + c4) * 128 + kk * 32 + quad * 8);

        float lsum = 0.f;        // row i = i0 + c4 partial (dup x4 quads)
        f32x4 oacc[8] = {};      // O[i = quad*4+r][c = n*16 + c4]

        // ---- prefetch tile 0 into buffer 0
#pragma unroll
        for (int t = 0; t < 8; t++) {
            int chunk = w * 8 + t;
            if (chunk < 16) {
                int np = chunk >> 2, kk = chunk & 3;
                gload_lds16(kp + (size_t)(np * 16 + c4) * 128 + kk * 32 + quad * 8,
                            &klds[chunk * 512]);
            } else {
                int cc = chunk - 16, n = cc >> 1, kw = cc & 1;
                gload_lds16(vp + (size_t)(n * 16 + c4) * 1024 + kw * 32 + quad * 8,
                            &vlds[cc * 512]);
            }
        }

        for (int jt = 0; jt < 16; jt++) {
            int cur = jt & 1;
            __syncthreads();   // staging of cur visible; prev reads of next-buf done
            // ---- issue prefetch for jt+1 (drained at NEXT barrier, after compute)
            if (jt < 15) {
                int j0n = (jt + 1) * 64, nb = cur ^ 1;
#pragma unroll
                for (int t = 0; t < 8; t++) {
                    int chunk = w * 8 + t;
                    if (chunk < 16) {
                        int np = chunk >> 2, kk = chunk & 3;
                        gload_lds16(kp + (size_t)(j0n + np * 16 + c4) * 128 + kk * 32 + quad * 8,
                                    &klds[nb * 8192 + chunk * 512]);
                    } else {
                        int cc = chunk - 16, n = cc >> 1, kw = cc & 1;
                        gload_lds16(vp + (size_t)(n * 16 + c4) * 1024 + j0n + kw * 32 + quad * 8,
                                    &vlds[nb * 8192 + cc * 512]);
                    }
                }
            }

            // ---- S^T: st[np], j = jt*64 + np*16 + quad*4 + r, i = i0 + c4
            f32x4 st[4] = {};
#pragma unroll
            for (int np = 0; np < 4; np++)
#pragma unroll
                for (int kk = 0; kk < 4; kk++) {
                    bf16x8 ak = *(const bf16x8*)&klds[cur * 8192 + (np * 4 + kk) * 512 + lane * 8];
                    st[np] = __builtin_amdgcn_mfma_f32_16x16x32_bf16(ak, bq[kk], st[np], 0, 0, 0);
                }

            // ---- p = exp2(s) (log2e folded into wq); accumulate row sums
#pragma unroll
            for (int np = 0; np < 4; np++)
#pragma unroll
                for (int r = 0; r < 4; r++) {
                    float p = exp2f(st[np][r]);
                    st[np][r] = p;
                    lsum += p;
                }

            // ---- pack np pairs; re-frag via shfl (dest-side half select)
            unsigned pk2[2][4];
#pragma unroll
            for (int kw = 0; kw < 2; kw++)
#pragma unroll
                for (int r = 0; r < 4; r++)
                    pk2[kw][r] = packbf(st[kw * 2][r], st[kw * 2 + 1][r]);

            int sbase = ((lane & 16) ? 32 : 0) + c4;
            bool hi = (lane & 32) != 0;
#pragma unroll
            for (int kw = 0; kw < 2; kw++) {
                bf16x8 pa;
#pragma unroll
                for (int t = 0; t < 4; t++) {
                    unsigned u  = (unsigned)__shfl((int)pk2[kw][t], sbase);
                    unsigned u2 = (unsigned)__shfl((int)pk2[kw][t], sbase + 16);
                    pa[t]     = (short)(hi ? (u >> 16)  : (u & 0xffffu));
                    pa[4 + t] = (short)(hi ? (u2 >> 16) : (u2 & 0xffffu));
                }
#pragma unroll
                for (int n = 0; n < 8; n++) {
                    bf16x8 bv = *(const bf16x8*)&vlds[cur * 8192 + (n * 2 + kw) * 512 + lane * 8];
                    oacc[n] = __builtin_amdgcn_mfma_f32_16x16x32_bf16(pa, bv, oacc[n], 0, 0, 0);
                }
            }
        }

        // ---- finish row sums (reduce over quads), epilogue
        lsum += __shfl_xor(lsum, 16);
        lsum += __shfl_xor(lsum, 32);
        float inv = 1.0f / lsum;
        float ir[4];
#pragma unroll
        for (int r = 0; r < 4; r++) ir[r] = __shfl(inv, quad * 4 + r);
#pragma unroll
        for (int n = 0; n < 8; n++)
#pragma unroll
            for (int r = 0; r < 4; r++) {
                int i = i0 + quad * 4 + r;
                int c = h * 128 + n * 16 + c4;
                ot[((size_t)b * 1024 + i) * 256 + c] = f2bf(oacc[n][r] * ir[r]);
            }
    }
    __threadfence();
    grid.sync();
    __threadfence();

    // ================= phase 3: proj + residual ============================
    {
        int b = bid >> 5, my = (bid >> 4) & 1, nx = bid & 15;
        int w = tid >> 6, lane = tid & 63, quad = lane >> 4, c4 = lane & 15;
        int wm = (w >> 1) * 64, wn = (w & 1) * 32;
        int mbase = my * 128 + wm;
        int nbase = nx * 64 + wn;
        const unsigned short* ob = ot + (size_t)b * 1024 * 256;

        f32x4 acc2[4][2] = {};
#pragma unroll
        for (int k = 0; k < 256; k += 32) {
            bf16x8 af[4], bfr[2];
#pragma unroll
            for (int i = 0; i < 4; i++)
                af[i] = *(const bf16x8*)(wpb + (mbase + i * 16 + c4) * 256 + k + quad * 8);
#pragma unroll
            for (int i = 0; i < 2; i++)
                bfr[i] = *(const bf16x8*)(ob + (size_t)(nbase + i * 16 + c4) * 256 + k + quad * 8);
#pragma unroll
            for (int mi = 0; mi < 4; mi++)
#pragma unroll
                for (int ni = 0; ni < 2; ni++)
                    acc2[mi][ni] = __builtin_amdgcn_mfma_f32_16x16x32_bf16(
                        af[mi], bfr[ni], acc2[mi][ni], 0, 0, 0);
        }
#pragma unroll
        for (int mi = 0; mi < 4; mi++)
#pragma unroll
            for (int ni = 0; ni < 2; ni++)
#pragma unroll
                for (int r = 0; r < 4; r++) {
                    int o = mbase + mi * 16 + quad * 4 + r;
                    int i = nbase + ni * 16 + c4;
                    size_t idx = ((size_t)b * 256 + o) * 1024 + i;
                    out[idx] = acc2[mi][ni][r] + x[idx];
                }
    }
}

// ======================= R6 fallback kernels (verified) ====================
__global__ __launch_bounds__(256) void prep(const float* __restrict__ wq,
                                            const float* __restrict__ wk,
                                            const float* __restrict__ wv,
                                            const float* __restrict__ wp,
                                            unsigned short* __restrict__ oq,
                                            unsigned short* __restrict__ ok,
                                            unsigned short* __restrict__ ov,
                                            unsigned short* __restrict__ op,
                                            const float* __restrict__ x,
                                            float* __restrict__ acc) {
    int bid = blockIdx.x;
    if (bid < 256) {
        int idx = bid * 1024 + threadIdx.x * 4;
        int which = idx >> 16, i = idx & 65535;
        const float* src = (which == 0) ? wq : (which == 1) ? wk : (which == 2) ? wv : wp;
        unsigned short* dst = (which == 0) ? oq : (which == 1) ? ok : (which == 2) ? ov : op;
        float scl = (which == 0) ? (0.044194173824159216f * 1.4426950408889634f) : 1.0f;
        float4 v = *(const float4*)(src + i);
        ushort4 o;
        o.x = f2bf(v.x * scl); o.y = f2bf(v.y * scl);
        o.z = f2bf(v.z * scl); o.w = f2bf(v.w * scl);
        *(ushort4*)(dst + i) = o;
    } else {
        int bid2 = bid - 256;
        int bg = bid2 >> 3, ch = bid2 & 7;
        const float4* xp = (const float4*)(x + (size_t)bg * 65536 + ch * 8192);
        float s = 0.f, s2 = 0.f;
#pragma unroll
        for (int i = 0; i < 8; i++) {
            float4 v = xp[threadIdx.x + i * 256];
            s  += v.x + v.y + v.z + v.w;
            s2 += v.x * v.x + v.y * v.y + v.z * v.z + v.w * v.w;
        }
        for (int m = 1; m < 64; m <<= 1) { s += __shfl_xor(s, m); s2 += __shfl_xor(s2, m); }
        __shared__ float ls[8];
        int w = threadIdx.x >> 6, lane = threadIdx.x & 63;
        if (lane == 0) { ls[w] = s; ls[4 + w] = s2; }
        __syncthreads();
        if (threadIdx.x == 0) {
            acc[bg * 16 + ch * 2]     = ls[0] + ls[1] + ls[2] + ls[3];
            acc[bg * 16 + ch * 2 + 1] = ls[4] + ls[5] + ls[6] + ls[7];
        }
    }
}

__global__ __launch_bounds__(256) void qkv_fused(const float* __restrict__ x,
                                                 const float* __restrict__ acc,
                                                 const float* __restrict__ gnw,
                                                 const float* __restrict__ gnb,
                                                 const unsigned short* __restrict__ wqb,
                                                 const unsigned short* __restrict__ wkb,
                                                 const unsigned short* __restrict__ wvb,
                                                 unsigned short* __restrict__ qt,
                                                 unsigned short* __restrict__ kt,
                                                 unsigned short* __restrict__ vv) {
    int b = blockIdx.z, half = blockIdx.y, nx = blockIdx.x;
    int n0 = nx * 64;
    int t = threadIdx.x, w = t >> 6, lane = t & 63, quad = lane >> 4, c4 = lane & 15;
    __shared__ __align__(16) unsigned short xl[17408];
    __shared__ __align__(16) unsigned short ebuf[9216];
    __shared__ float gs[8];
    if (t < 4) {
        float s0 = 0.f, s1 = 0.f;
#pragma unroll
        for (int p = 0; p < 8; p++) {
            s0 += acc[(b * 4 + t) * 16 + p * 2];
            s1 += acc[(b * 4 + t) * 16 + p * 2 + 1];
        }
        float mean = s0 * (1.f / 65536.f);
        float var = s1 * (1.f / 65536.f) - mean * mean;
        gs[2 * t] = mean;
        gs[2 * t + 1] = rsqrtf(var + 1e-5f);
    }
    __syncthreads();
    {
        int col = t & 15, crow = t >> 4;
#pragma unroll
        for (int p = 0; p < 16; p++) {
            int c = p * 16 + crow;
            int g = c >> 6;
            float sc = gs[g * 2 + 1] * gnw[c];
            float bs = gnb[c] - gs[g * 2] * sc;
            float4 v = *(const float4*)(x + ((size_t)b * 256 + c) * 1024 + n0 + col * 4);
            int nl = col * 4;
            xl[(nl + 0) * 264 + c] = (unsigned short)(bfbits(fmaf(v.x, sc, bs)) >> 16);
            xl[(nl + 1) * 264 + c] = (unsigned short)(bfbits(fmaf(v.y, sc, bs)) >> 16);
            xl[(nl + 2) * 264 + c] = (unsigned short)(bfbits(fmaf(v.z, sc, bs)) >> 16);
            xl[(nl + 3) * 264 + c] = (unsigned short)(bfbits(fmaf(v.w, sc, bs)) >> 16);
        }
    }
    __syncthreads();
    int wm = (w >> 1) * 64, wn = (w & 1) * 32;
    int mbase = half * 128 + wm;
    int bh = b * 2 + half;
    f32x4 aq[4][2] = {}, akk[4][2] = {}, av[4][2] = {};
#pragma unroll
    for (int k = 0; k < 256; k += 32) {
        bf16x8 bfr[2];
#pragma unroll
        for (int i = 0; i < 2; i++)
            bfr[i] = *(const bf16x8*)&xl[(wn + i * 16 + c4) * 264 + k + quad * 8];
#pragma unroll
        for (int mi = 0; mi < 4; mi++) {
            bf16x8 afq = *(const bf16x8*)(wqb + (mbase + mi * 16 + c4) * 256 + k + quad * 8);
            bf16x8 afk = *(const bf16x8*)(wkb + (mbase + mi * 16 + c4) * 256 + k + quad * 8);
            bf16x8 afv = *(const bf16x8*)(wvb + (mbase + mi * 16 + c4) * 256 + k + quad * 8);
#pragma unroll
            for (int ni = 0; ni < 2; ni++) {
                aq[mi][ni]  = __builtin_amdgcn_mfma_f32_16x16x32_bf16(afq, bfr[ni], aq[mi][ni], 0, 0, 0);
                akk[mi][ni] = __builtin_amdgcn_mfma_f32_16x16x32_bf16(afk, bfr[ni], akk[mi][ni], 0, 0, 0);
                av[mi][ni]  = __builtin_amdgcn_mfma_f32_16x16x32_bf16(afv, bfr[ni], av[mi][ni], 0, 0, 0);
            }
        }
    }
    __syncthreads();
#pragma unroll
    for (int mi = 0; mi < 4; mi++)
#pragma unroll
        for (int ni = 0; ni < 2; ni++) {
            int row = wn + ni * 16 + c4;
            int col = wm + mi * 16 + quad * 4;
            uint2 uq, uk;
            uq.x = packbf(aq[mi][ni][0], aq[mi][ni][1]);
            uq.y = packbf(aq[mi][ni][2], aq[mi][ni][3]);
            uk.x = packbf(akk[mi][ni][0], akk[mi][ni][1]);
            uk.y = packbf(akk[mi][ni][2], akk[mi][ni][3]);
            *(uint2*)&xl[row * 136 + col] = uq;
            *(uint2*)&xl[8704 + row * 136 + col] = uk;
#pragma unroll
            for (int r = 0; r < 4; r++)
                ebuf[(col + r) * 72 + row] = f2bf(av[mi][ni][r]);
        }
    __syncthreads();
#pragma unroll
    for (int p = 0; p < 4; p++) {
        int i = p * 16 + (t >> 4), off = (t & 15) * 8;
        *(bf16x8*)(qt + ((size_t)bh * 1024 + n0 + i) * 128 + off) =
            *(const bf16x8*)&xl[i * 136 + off];
        *(bf16x8*)(kt + ((size_t)bh * 1024 + n0 + i) * 128 + off) =
            *(const bf16x8*)&xl[8704 + i * 136 + off];
    }
#pragma unroll
    for (int p = 0; p < 4; p++) {
        int ch = p * 32 + (t >> 3), off = (t & 7) * 8;
        *(bf16x8*)(vv + ((size_t)bh * 128 + ch) * 1024 + n0 + off) =
            *(const bf16x8*)&ebuf[ch * 72 + off];
    }
}

__global__ __launch_bounds__(256) void attn_kernel(const unsigned short* __restrict__ qt,
                                                   const unsigned short* __restrict__ kt,
                                                   const unsigned short* __restrict__ vv,
                                                   unsigned short* __restrict__ ot) {
    int L = blockIdx.x;
    int xcd = L & 7, jj = L >> 3;
    int bh = (jj >> 4) * 8 + xcd;
    int qb = jj & 15;
    int b = bh >> 1, h = bh & 1;
    int tid = threadIdx.x, w = tid >> 6, lane = tid & 63;
    int quad = lane >> 4, c4 = lane & 15;
    __shared__ __align__(16) unsigned short klds[2][8192];
    __shared__ __align__(16) unsigned short vlds[2][8192];

    const unsigned short* qp = qt + (size_t)bh * 1024 * 128;
    const unsigned short* kp = kt + (size_t)bh * 1024 * 128;
    const unsigned short* vp = vv + (size_t)bh * 128 * 1024;
    int i0 = qb * 64 + w * 16;

    bf16x8 bq[4];
#pragma unroll
    for (int kk = 0; kk < 4; kk++)
        bq[kk] = *(const bf16x8*)(qp + (size_t)(i0 + c4) * 128 + kk * 32 + quad * 8);

    float lsum = 0.f;
    f32x4 oacc[8] = {};

#pragma unroll
    for (int t = 0; t < 8; t++) {
        int chunk = w * 8 + t;
        if (chunk < 16) {
            int np = chunk >> 2, kk = chunk & 3;
            gload_lds16(kp + (size_t)(np * 16 + c4) * 128 + kk * 32 + quad * 8,
                        &klds[0][chunk * 512]);
        } else {
            int cc = chunk - 16, n = cc >> 1, kw = cc & 1;
            gload_lds16(vp + (size_t)(n * 16 + c4) * 1024 + kw * 32 + quad * 8,
                        &vlds[0][cc * 512]);
        }
    }

    for (int jt = 0; jt < 16; jt++) {
        int cur = jt & 1;
        __syncthreads();
        if (jt < 15) {
            int j0n = (jt + 1) * 64, nb = cur ^ 1;
#pragma unroll
            for (int t = 0; t < 8; t++) {
                int chunk = w * 8 + t;
                if (chunk < 16) {
                    int np = chunk >> 2, kk = chunk & 3;
                    gload_lds16(kp + (size_t)(j0n + np * 16 + c4) * 128 + kk * 32 + quad * 8,
                                &klds[nb][chunk * 512]);
                } else {
                    int cc = chunk - 16, n = cc >> 1, kw = cc & 1;
                    gload_lds16(vp + (size_t)(n * 16 + c4) * 1024 + j0n + kw * 32 + quad * 8,
                                &vlds[nb][cc * 512]);
                }
            }
        }

        f32x4 st[4] = {};
#pragma unroll
        for (int np = 0; np < 4; np++)
#pragma unroll
            for (int kk = 0; kk < 4; kk++) {
                bf16x8 ak = *(const bf16x8*)&klds[cur][(np * 4 + kk) * 512 + lane * 8];
                st[np] = __builtin_amdgcn_mfma_f32_16x16x32_bf16(ak, bq[kk], st[np], 0, 0, 0);
            }

#pragma unroll
        for (int np = 0; np < 4; np++)
#pragma unroll
            for (int r = 0; r < 4; r++) {
                float p = exp2f(st[np][r]);
                st[np][r] = p;
                lsum += p;
            }

        unsigned pk2[2][4];
#pragma unroll
        for (int kw = 0; kw < 2; kw++)
#pragma unroll
            for (int r = 0; r < 4; r++)
                pk2[kw][r] = packbf(st[kw * 2][r], st[kw * 2 + 1][r]);

        int sbase = ((lane & 16) ? 32 : 0) + c4;
        bool hi = (lane & 32) != 0;
#pragma unroll
        for (int kw = 0; kw < 2; kw++) {
            bf16x8 pa;
#pragma unroll
            for (int t = 0; t < 4; t++) {
                unsigned u  = (unsigned)__shfl((int)pk2[kw][t], sbase);
                unsigned u2 = (unsigned)__shfl((int)pk2[kw][t], sbase + 16);
                pa[t]     = (short)(hi ? (u >> 16)  : (u & 0xffffu));
                pa[4 + t] = (short)(hi ? (u2 >> 16) : (u2 & 0xffffu));
            }
#pragma unroll
            for (int n = 0; n < 8; n++) {
                bf16x8 bv = *(const bf16x8*)&vlds[cur][(n * 2 + kw) * 512 + lane * 8];
                oacc[n] = __builtin_amdgcn_mfma_f32_16x16x32_bf16(pa, bv, oacc[n], 0, 0, 0);
            }
        }
    }

    lsum += __shfl_xor(lsum, 16);
    lsum += __shfl_xor(lsum, 32);
    float inv = 1.0f / lsum;
    float ir[4];
#pragma unroll
    for (int r = 0; r < 4; r++) ir[r] = __shfl(inv, quad * 4 + r);
#pragma unroll
    for (int n = 0; n < 8; n++)
#pragma unroll
        for (int r = 0; r < 4; r++) {
            int i = i0 + quad * 4 + r;
            int c = h * 128 + n * 16 + c4;
            ot[((size_t)b * 1024 + i) * 256 + c] = f2bf(oacc[n][r] * ir[r]);
        }
}

__global__ __launch_bounds__(256) void proj_gemm(const unsigned short* __restrict__ wpb,
                                                 const unsigned short* __restrict__ ot,
                                                 const float* __restrict__ x,
                                                 float* __restrict__ out) {
    int b = blockIdx.z;
    int my = blockIdx.y;
    int nx = blockIdx.x;
    int tid = threadIdx.x;
    int w = tid >> 6, lane = tid & 63, quad = lane >> 4, c4 = lane & 15;
    int wm = (w >> 1) * 64, wn = (w & 1) * 32;
    int mbase = my * 128 + wm;
    int nbase = nx * 64 + wn;
    const unsigned short* ob = ot + (size_t)b * 1024 * 256;

    f32x4 acc[4][2] = {};
#pragma unroll
    for (int k = 0; k < 256; k += 32) {
        bf16x8 af[4], bfr[2];
#pragma unroll
        for (int i = 0; i < 4; i++)
            af[i] = *(const bf16x8*)(wpb + (mbase + i * 16 + c4) * 256 + k + quad * 8);
#pragma unroll
        for (int i = 0; i < 2; i++)
            bfr[i] = *(const bf16x8*)(ob + (size_t)(nbase + i * 16 + c4) * 256 + k + quad * 8);
#pragma unroll
        for (int mi = 0; mi < 4; mi++)
#pragma unroll
            for (int ni = 0; ni < 2; ni++)
                acc[mi][ni] = __builtin_amdgcn_mfma_f32_16x16x32_bf16(
                    af[mi], bfr[ni], acc[mi][ni], 0, 0, 0);
    }
#pragma unroll
    for (int mi = 0; mi < 4; mi++)
#pragma unroll
        for (int ni = 0; ni < 2; ni++)
#pragma unroll
            for (int r = 0; r < 4; r++) {
                int o = mbase + mi * 16 + quad * 4 + r;
                int i = nbase + ni * 16 + c4;
                size_t idx = ((size_t)b * 256 + o) * 1024 + i;
                out[idx] = acc[mi][ni][r] + x[idx];
            }
}

// ---------------------------------------------------------------------------
extern "C" void kernel_launch(void* const* d_in, const int* in_sizes, int n_in,
                              void* d_out, int out_size, void* d_ws, size_t ws_size,
                              hipStream_t stream) {
    const float* x   = (const float*)d_in[0];
    const float* gnw = (const float*)d_in[1];
    const float* gnb = (const float*)d_in[2];
    const float* wq  = (const float*)d_in[3];
    const float* wk  = (const float*)d_in[4];
    const float* wv  = (const float*)d_in[5];
    const float* wp  = (const float*)d_in[6];
    float* out = (float*)d_out;

    char* ws = (char*)d_ws;
    float* acc = (float*)ws;                                        //   4 KiB
    unsigned short* wqb = (unsigned short*)(ws + 4096);             // 128 KiB each
    unsigned short* wkb = (unsigned short*)(ws + 4096 + 131072);
    unsigned short* wvb = (unsigned short*)(ws + 4096 + 2 * 131072);
    unsigned short* wpb = (unsigned short*)(ws + 4096 + 3 * 131072);
    size_t base = 4096 + 4 * 131072;
    const size_t SZ = (size_t)16 * 1024 * 256 * 2;  // 8 MiB each
    unsigned short* qt = (unsigned short*)(ws + base);
    unsigned short* kt = (unsigned short*)(ws + base + SZ);
    unsigned short* vv = (unsigned short*)(ws + base + 2 * SZ);
    unsigned short* ot = (unsigned short*)(ws + base + 3 * SZ);

    void* args[] = {
        (void*)&x, (void*)&gnw, (void*)&gnb,
        (void*)&wq, (void*)&wk, (void*)&wv, (void*)&wp,
        (void*)&acc,
        (void*)&wqb, (void*)&wkb, (void*)&wvb, (void*)&wpb,
        (void*)&qt, (void*)&kt, (void*)&vv, (void*)&ot,
        (void*)&out,
    };
    hipError_t rc = hipLaunchCooperativeKernel((void*)fused_all, dim3(512),
                                               dim3(256), args, 0, stream);
    if (rc != hipSuccess) {
        (void)hipGetLastError();   // clear sticky error, use verified 4-kernel path
        prep<<<768, 256, 0, stream>>>(wq, wk, wv, wp, wqb, wkb, wvb, wpb, x, acc);
        qkv_fused<<<dim3(16, 2, 16), 256, 0, stream>>>(x, acc, gnw, gnb,
                                                       wqb, wkb, wvb, qt, kt, vv);
        attn_kernel<<<512, 256, 0, stream>>>(qt, kt, vv, ot);
        proj_gemm<<<dim3(16, 2, 16), 256, 0, stream>>>(wpb, ot, x, out);
    }
}

// Round 6
// 211.366 us; speedup vs baseline: 2.5886x; 2.5886x over previous
//
#include <hip/hip_runtime.h>
#include <math.h>

// ---------------------------------------------------------------------------
// AttentionBlock: GN(4,256) -> QKV 1x1 conv -> 2-head attn (N=1024, hd=128)
// -> proj -> +residual.  B=16, C=256, H=W=32 (N=1024), fp32 in/out.
// R9: 3 kernels. prep + qkv verbatim from R6 (165.9us verified). attn_proj
// fuses attention(both heads)+proj per block: 256 blocks x 512 thr (8 waves,
// waves 0-3 head0 / 4-7 head1 concurrently), K double-buffered in LDS for
// both heads (64KB), V read DIRECT from global (L2-resident by XCD swizzle;
// R6's V-staging was an address-preserving pass-through). After flash, LDS
// reused as O-tile [64][264] bf16; proj GEMM + residual fused in-block.
// R7/R8 lesson: cooperative grid.sync costs ~100us/sync on MI355X -> dead.
// ---------------------------------------------------------------------------

typedef __attribute__((ext_vector_type(8))) short bf16x8;   // 8 bf16 = 4 VGPRs
typedef __attribute__((ext_vector_type(4))) float f32x4;

__device__ __forceinline__ unsigned short f2bf(float f) {   // RNE-ish
    union { float f; unsigned u; } v; v.f = f;
    return (unsigned short)((v.u + 0x7FFFu + ((v.u >> 16) & 1u)) >> 16);
}
__device__ __forceinline__ unsigned bfbits(float f) {       // +half (round up)
    union { float f; unsigned u; } v; v.f = f;
    return v.u + 0x8000u;
}
// pack two floats -> (bf(a) | bf(b)<<16) in 3 VALU ops
__device__ __forceinline__ unsigned packbf(float a, float b) {
    return __builtin_amdgcn_perm(bfbits(b), bfbits(a), 0x07060302u);
}

__device__ __forceinline__ void gload_lds16(const void* g, void* l) {
    __builtin_amdgcn_global_load_lds(
        (const __attribute__((address_space(1))) unsigned int*)g,
        (__attribute__((address_space(3))) unsigned int*)l, 16, 0, 0);
}

// ------------------------------------------- prep: weights->bf16 + GN stats
__global__ __launch_bounds__(256) void prep(const float* __restrict__ wq,
                                            const float* __restrict__ wk,
                                            const float* __restrict__ wv,
                                            const float* __restrict__ wp,
                                            unsigned short* __restrict__ oq,
                                            unsigned short* __restrict__ ok,
                                            unsigned short* __restrict__ ov,
                                            unsigned short* __restrict__ op,
                                            const float* __restrict__ x,
                                            float* __restrict__ acc) {
    int bid = blockIdx.x;
    if (bid < 256) {
        int idx = bid * 1024 + threadIdx.x * 4;
        int which = idx >> 16, i = idx & 65535;
        const float* src = (which == 0) ? wq : (which == 1) ? wk : (which == 2) ? wv : wp;
        unsigned short* dst = (which == 0) ? oq : (which == 1) ? ok : (which == 2) ? ov : op;
        // fold softmax scale 512^-0.5 AND log2(e) into wq (softmax uses exp2)
        float scl = (which == 0) ? (0.044194173824159216f * 1.4426950408889634f) : 1.0f;
        float4 v = *(const float4*)(src + i);
        ushort4 o;
        o.x = f2bf(v.x * scl); o.y = f2bf(v.y * scl);
        o.z = f2bf(v.z * scl); o.w = f2bf(v.w * scl);
        *(ushort4*)(dst + i) = o;
    } else {
        int bid2 = bid - 256;                  // [0,512)
        int bg = bid2 >> 3, ch = bid2 & 7;
        const float4* xp = (const float4*)(x + (size_t)bg * 65536 + ch * 8192);
        float s = 0.f, s2 = 0.f;
#pragma unroll
        for (int i = 0; i < 8; i++) {
            float4 v = xp[threadIdx.x + i * 256];
            s  += v.x + v.y + v.z + v.w;
            s2 += v.x * v.x + v.y * v.y + v.z * v.z + v.w * v.w;
        }
        for (int m = 1; m < 64; m <<= 1) { s += __shfl_xor(s, m); s2 += __shfl_xor(s2, m); }
        __shared__ float ls[8];
        int w = threadIdx.x >> 6, lane = threadIdx.x & 63;
        if (lane == 0) { ls[w] = s; ls[4 + w] = s2; }
        __syncthreads();
        if (threadIdx.x == 0) {
            acc[bg * 16 + ch * 2]     = ls[0] + ls[1] + ls[2] + ls[3];
            acc[bg * 16 + ch * 2 + 1] = ls[4] + ls[5] + ls[6] + ls[7];
        }
    }
}

// --------------------------------------------------- QKV GEMM fused with GN
__global__ __launch_bounds__(256) void qkv_fused(const float* __restrict__ x,
                                                 const float* __restrict__ acc,
                                                 const float* __restrict__ gnw,
                                                 const float* __restrict__ gnb,
                                                 const unsigned short* __restrict__ wqb,
                                                 const unsigned short* __restrict__ wkb,
                                                 const unsigned short* __restrict__ wvb,
                                                 unsigned short* __restrict__ qt,
                                                 unsigned short* __restrict__ kt,
                                                 unsigned short* __restrict__ vv) {
    int b = blockIdx.z, half = blockIdx.y, nx = blockIdx.x;
    int n0 = nx * 64;
    int t = threadIdx.x, w = t >> 6, lane = t & 63, quad = lane >> 4, c4 = lane & 15;
    __shared__ __align__(16) unsigned short xl[17408];   // p1: [64][264]; p2: Q-et@0, K-et@8704 ([64][136])
    __shared__ __align__(16) unsigned short ebuf[9216];  // V-et2 [128][72]
    __shared__ float gs[8];
    if (t < 4) {
        float s0 = 0.f, s1 = 0.f;
#pragma unroll
        for (int p = 0; p < 8; p++) {
            s0 += acc[(b * 4 + t) * 16 + p * 2];
            s1 += acc[(b * 4 + t) * 16 + p * 2 + 1];
        }
        float mean = s0 * (1.f / 65536.f);
        float var = s1 * (1.f / 65536.f) - mean * mean;
        gs[2 * t] = mean;
        gs[2 * t + 1] = rsqrtf(var + 1e-5f);
    }
    __syncthreads();
    // ---- load + normalize x-tile -> xl [n 64][c pitch 264]
    {
        int col = t & 15, crow = t >> 4;
#pragma unroll
        for (int p = 0; p < 16; p++) {
            int c = p * 16 + crow;
            int g = c >> 6;
            float sc = gs[g * 2 + 1] * gnw[c];
            float bs = gnb[c] - gs[g * 2] * sc;
            float4 v = *(const float4*)(x + ((size_t)b * 256 + c) * 1024 + n0 + col * 4);
            int nl = col * 4;
            xl[(nl + 0) * 264 + c] = (unsigned short)(bfbits(fmaf(v.x, sc, bs)) >> 16);
            xl[(nl + 1) * 264 + c] = (unsigned short)(bfbits(fmaf(v.y, sc, bs)) >> 16);
            xl[(nl + 2) * 264 + c] = (unsigned short)(bfbits(fmaf(v.z, sc, bs)) >> 16);
            xl[(nl + 3) * 264 + c] = (unsigned short)(bfbits(fmaf(v.w, sc, bs)) >> 16);
        }
    }
    __syncthreads();
    int wm = (w >> 1) * 64, wn = (w & 1) * 32;
    int mbase = half * 128 + wm;
    int bh = b * 2 + half;
    f32x4 aq[4][2] = {}, akk[4][2] = {}, av[4][2] = {};
#pragma unroll
    for (int k = 0; k < 256; k += 32) {
        bf16x8 bfr[2];
#pragma unroll
        for (int i = 0; i < 2; i++)
            bfr[i] = *(const bf16x8*)&xl[(wn + i * 16 + c4) * 264 + k + quad * 8];
#pragma unroll
        for (int mi = 0; mi < 4; mi++) {
            bf16x8 afq = *(const bf16x8*)(wqb + (mbase + mi * 16 + c4) * 256 + k + quad * 8);
            bf16x8 afk = *(const bf16x8*)(wkb + (mbase + mi * 16 + c4) * 256 + k + quad * 8);
            bf16x8 afv = *(const bf16x8*)(wvb + (mbase + mi * 16 + c4) * 256 + k + quad * 8);
#pragma unroll
            for (int ni = 0; ni < 2; ni++) {
                aq[mi][ni]  = __builtin_amdgcn_mfma_f32_16x16x32_bf16(afq, bfr[ni], aq[mi][ni], 0, 0, 0);
                akk[mi][ni] = __builtin_amdgcn_mfma_f32_16x16x32_bf16(afk, bfr[ni], akk[mi][ni], 0, 0, 0);
                av[mi][ni]  = __builtin_amdgcn_mfma_f32_16x16x32_bf16(afv, bfr[ni], av[mi][ni], 0, 0, 0);
            }
        }
    }
    __syncthreads();   // xl reads done; reuse xl + ebuf for epilogue
#pragma unroll
    for (int mi = 0; mi < 4; mi++)
#pragma unroll
        for (int ni = 0; ni < 2; ni++) {
            int row = wn + ni * 16 + c4;          // i-local
            int col = wm + mi * 16 + quad * 4;    // ch
            uint2 uq, uk;
            uq.x = packbf(aq[mi][ni][0], aq[mi][ni][1]);
            uq.y = packbf(aq[mi][ni][2], aq[mi][ni][3]);
            uk.x = packbf(akk[mi][ni][0], akk[mi][ni][1]);
            uk.y = packbf(akk[mi][ni][2], akk[mi][ni][3]);
            *(uint2*)&xl[row * 136 + col] = uq;
            *(uint2*)&xl[8704 + row * 136 + col] = uk;
#pragma unroll
            for (int r = 0; r < 4; r++)
                ebuf[(col + r) * 72 + row] = f2bf(av[mi][ni][r]);
        }
    __syncthreads();
#pragma unroll
    for (int p = 0; p < 4; p++) {
        int i = p * 16 + (t >> 4), off = (t & 15) * 8;
        *(bf16x8*)(qt + ((size_t)bh * 1024 + n0 + i) * 128 + off) =
            *(const bf16x8*)&xl[i * 136 + off];
        *(bf16x8*)(kt + ((size_t)bh * 1024 + n0 + i) * 128 + off) =
            *(const bf16x8*)&xl[8704 + i * 136 + off];
    }
#pragma unroll
    for (int p = 0; p < 4; p++) {
        int ch = p * 32 + (t >> 3), off = (t & 7) * 8;
        *(bf16x8*)(vv + ((size_t)bh * 128 + ch) * 1024 + n0 + off) =
            *(const bf16x8*)&ebuf[ch * 72 + off];
    }
}

// -------------------------------------- fused attention (both heads) + proj
// grid 256 (16 qb x 16 b, XCD-swizzled), 512 threads = 8 waves.
// waves 0-3: head 0, waves 4-7: head 1 (concurrent). K double-buffered in
// LDS for both heads (2 x 2 x 16KB = 64KB). V direct from global (L2-res).
// After flash: smem reused as O-tile [64][264] bf16 -> proj GEMM + residual.
__global__ __launch_bounds__(512) void attn_proj(const unsigned short* __restrict__ qt,
                                                 const unsigned short* __restrict__ kt,
                                                 const unsigned short* __restrict__ vv,
                                                 const unsigned short* __restrict__ wpb,
                                                 const float* __restrict__ x,
                                                 float* __restrict__ out) {
    int L = blockIdx.x;
    int xcd = L & 7, jj = L >> 3;          // jj in [0,32)
    int b = ((jj >> 4) << 3) | xcd;        // batches {xcd, xcd+8} per XCD
    int qb = jj & 15;
    int tid = threadIdx.x, w = tid >> 6, lane = tid & 63;
    int quad = lane >> 4, c4 = lane & 15;
    int h = w >> 2, wl = w & 3;            // head, wave-in-head
    int bh = b * 2 + h;
    __shared__ __align__(16) unsigned short smem[32768];   // 64 KiB exactly

    const unsigned short* qp = qt + (size_t)bh * 131072;
    const unsigned short* vp = vv + (size_t)bh * 131072;
    int i0 = qb * 64 + wl * 16;

    // Q B-frags (16 rows) in regs: i = i0 + c4, k = kk*32 + quad*8
    bf16x8 bq[4];
#pragma unroll
    for (int kk = 0; kk < 4; kk++)
        bq[kk] = *(const bf16x8*)(qp + (size_t)(i0 + c4) * 128 + kk * 32 + quad * 8);

    float lsum = 0.f;        // row i = i0 + c4 partial (dup x4 quads)
    f32x4 oacc[8] = {};      // O[i = quad*4+r][c = n*16 + c4]

    // ---- prefetch K tile 0 (both heads) into buffer 0: 32 chunks, 4/thread
#pragma unroll
    for (int t = 0; t < 4; t++) {
        int cc = w * 4 + t;                // [0,32)
        int h2 = cc >> 4, kc = cc & 15;
        int np = kc >> 2, kk = kc & 3;
        const unsigned short* kp2 = kt + (size_t)(b * 2 + h2) * 131072;
        gload_lds16(kp2 + (size_t)(np * 16 + c4) * 128 + kk * 32 + quad * 8,
                    &smem[h2 * 8192 + kc * 512]);
    }

    for (int jt = 0; jt < 16; jt++) {
        int cur = jt & 1;
        int j0 = jt * 64;
        __syncthreads();   // staging of cur visible; prev reads of next-buf done
        // ---- issue K prefetch for jt+1 (drains at NEXT barrier)
        if (jt < 15) {
            int j0n = j0 + 64, nb = cur ^ 1;
#pragma unroll
            for (int t = 0; t < 4; t++) {
                int cc = w * 4 + t;
                int h2 = cc >> 4, kc = cc & 15;
                int np = kc >> 2, kk = kc & 3;
                const unsigned short* kp2 = kt + (size_t)(b * 2 + h2) * 131072;
                gload_lds16(kp2 + (size_t)(j0n + np * 16 + c4) * 128 + kk * 32 + quad * 8,
                            &smem[nb * 16384 + h2 * 8192 + kc * 512]);
            }
        }

        // ---- S^T: st[np], j = j0 + np*16 + quad*4 + r, i = i0 + c4
        f32x4 st[4] = {};
#pragma unroll
        for (int np = 0; np < 4; np++)
#pragma unroll
            for (int kk = 0; kk < 4; kk++) {
                bf16x8 ak = *(const bf16x8*)&smem[cur * 16384 + h * 8192 + (np * 4 + kk) * 512 + lane * 8];
                st[np] = __builtin_amdgcn_mfma_f32_16x16x32_bf16(ak, bq[kk], st[np], 0, 0, 0);
            }

        // ---- p = exp2(s) (log2e folded into wq); accumulate row sums
#pragma unroll
        for (int np = 0; np < 4; np++)
#pragma unroll
            for (int r = 0; r < 4; r++) {
                float p = exp2f(st[np][r]);
                st[np][r] = p;
                lsum += p;
            }

        // ---- pack np pairs; re-frag via shfl (dest-side half select)
        unsigned pk2[2][4];
#pragma unroll
        for (int kw = 0; kw < 2; kw++)
#pragma unroll
            for (int r = 0; r < 4; r++)
                pk2[kw][r] = packbf(st[kw * 2][r], st[kw * 2 + 1][r]);

        int sbase = ((lane & 16) ? 32 : 0) + c4;
        bool hi = (lane & 32) != 0;
#pragma unroll
        for (int kw = 0; kw < 2; kw++) {
            bf16x8 pa;
#pragma unroll
            for (int t = 0; t < 4; t++) {
                unsigned u  = (unsigned)__shfl((int)pk2[kw][t], sbase);
                unsigned u2 = (unsigned)__shfl((int)pk2[kw][t], sbase + 16);
                pa[t]     = (short)(hi ? (u >> 16)  : (u & 0xffffu));
                pa[4 + t] = (short)(hi ? (u2 >> 16) : (u2 & 0xffffu));
            }
            // V B-frags DIRECT from global (address-identical to R6 staging)
#pragma unroll
            for (int n = 0; n < 8; n++) {
                bf16x8 bv = *(const bf16x8*)(vp + (size_t)(n * 16 + c4) * 1024 + j0 + kw * 32 + quad * 8);
                oacc[n] = __builtin_amdgcn_mfma_f32_16x16x32_bf16(pa, bv, oacc[n], 0, 0, 0);
            }
        }
    }

    // ---- finish row sums (reduce over quads)
    lsum += __shfl_xor(lsum, 16);
    lsum += __shfl_xor(lsum, 32);
    float inv = 1.0f / lsum;
    float ir[4];
#pragma unroll
    for (int r = 0; r < 4; r++) ir[r] = __shfl(inv, quad * 4 + r);

    __syncthreads();   // all K-LDS reads done -> reuse smem as O-tile
    // ---- write O tile [64 rows][264 pitch], c = h*128 + n*16 + c4
#pragma unroll
    for (int n = 0; n < 8; n++)
#pragma unroll
        for (int r = 0; r < 4; r++) {
            int il = wl * 16 + quad * 4 + r;
            int c = h * 128 + n * 16 + c4;
            smem[il * 264 + c] = f2bf(oacc[n][r] * ir[r]);
        }
    __syncthreads();

    // ---- proj + residual: wave w owns output channels [w*32, w*32+32)
    int mbase = w * 32;
    f32x4 pacc[2][4] = {};
#pragma unroll
    for (int k = 0; k < 256; k += 32) {
        bf16x8 af[2], bfr[4];
#pragma unroll
        for (int mi = 0; mi < 2; mi++)
            af[mi] = *(const bf16x8*)(wpb + (size_t)(mbase + mi * 16 + c4) * 256 + k + quad * 8);
#pragma unroll
        for (int ni = 0; ni < 4; ni++)
            bfr[ni] = *(const bf16x8*)&smem[(ni * 16 + c4) * 264 + k + quad * 8];
#pragma unroll
        for (int mi = 0; mi < 2; mi++)
#pragma unroll
            for (int ni = 0; ni < 4; ni++)
                pacc[mi][ni] = __builtin_amdgcn_mfma_f32_16x16x32_bf16(
                    af[mi], bfr[ni], pacc[mi][ni], 0, 0, 0);
    }
#pragma unroll
    for (int mi = 0; mi < 2; mi++)
#pragma unroll
        for (int ni = 0; ni < 4; ni++)
#pragma unroll
            for (int r = 0; r < 4; r++) {
                int o = mbase + mi * 16 + quad * 4 + r;
                int i = qb * 64 + ni * 16 + c4;
                size_t idx = ((size_t)b * 256 + o) * 1024 + i;
                out[idx] = pacc[mi][ni][r] + x[idx];
            }
}

// ---------------------------------------------------------------------------
extern "C" void kernel_launch(void* const* d_in, const int* in_sizes, int n_in,
                              void* d_out, int out_size, void* d_ws, size_t ws_size,
                              hipStream_t stream) {
    const float* x   = (const float*)d_in[0];
    const float* gnw = (const float*)d_in[1];
    const float* gnb = (const float*)d_in[2];
    const float* wq  = (const float*)d_in[3];
    const float* wk  = (const float*)d_in[4];
    const float* wv  = (const float*)d_in[5];
    const float* wp  = (const float*)d_in[6];
    float* out = (float*)d_out;

    char* ws = (char*)d_ws;
    float* acc = (float*)ws;                                        //   4 KiB
    unsigned short* wqb = (unsigned short*)(ws + 4096);             // 128 KiB each
    unsigned short* wkb = (unsigned short*)(ws + 4096 + 131072);
    unsigned short* wvb = (unsigned short*)(ws + 4096 + 2 * 131072);
    unsigned short* wpb = (unsigned short*)(ws + 4096 + 3 * 131072);
    size_t base = 4096 + 4 * 131072;
    const size_t SZ = (size_t)16 * 1024 * 256 * 2;  // 8 MiB each
    unsigned short* qt = (unsigned short*)(ws + base);
    unsigned short* kt = (unsigned short*)(ws + base + SZ);
    unsigned short* vv = (unsigned short*)(ws + base + 2 * SZ);

    prep<<<768, 256, 0, stream>>>(wq, wk, wv, wp, wqb, wkb, wvb, wpb, x, acc);
    qkv_fused<<<dim3(16, 2, 16), 256, 0, stream>>>(x, acc, gnw, gnb,
                                                   wqb, wkb, wvb, qt, kt, vv);
    attn_proj<<<256, 512, 0, stream>>>(qt, kt, vv, wpb, x, out);
}

// Round 7
// 183.901 us; speedup vs baseline: 2.9752x; 1.1493x over previous
//
#include <hip/hip_runtime.h>
#include <math.h>

// ---------------------------------------------------------------------------
// AttentionBlock: GN(4,256) -> QKV 1x1 conv -> 2-head attn (N=1024, hd=128)
// -> proj -> +residual.  B=16, C=256, H=W=32 (N=1024), fp32 in/out.
// R10: prep + qkv verbatim R6. attn_proj2 = R6 flash attention EXACT (512
// blocks x 256 thr, one (bh,qb)/block, K+V dbuf gload_lds, 2 blocks/CU) +
// fused partial proj: each head-block GEMMs its 128-channel half of wp
// against its O-tile (LDS) and unsafeAtomicAdd's fp32 partials into out
// (h==0 adds residual x). 2 commutative adds/element = deterministic.
// R9 lesson: 512-thr/64KB blocks pack 2/CU -> half the CUs idle (Occ 21%);
// V-direct-from-global quadruples L2 V-traffic. Both reverted here.
// ---------------------------------------------------------------------------

typedef __attribute__((ext_vector_type(8))) short bf16x8;   // 8 bf16 = 4 VGPRs
typedef __attribute__((ext_vector_type(4))) float f32x4;

__device__ __forceinline__ unsigned short f2bf(float f) {   // RNE-ish
    union { float f; unsigned u; } v; v.f = f;
    return (unsigned short)((v.u + 0x7FFFu + ((v.u >> 16) & 1u)) >> 16);
}
__device__ __forceinline__ unsigned bfbits(float f) {       // +half (round up)
    union { float f; unsigned u; } v; v.f = f;
    return v.u + 0x8000u;
}
// pack two floats -> (bf(a) | bf(b)<<16) in 3 VALU ops
__device__ __forceinline__ unsigned packbf(float a, float b) {
    return __builtin_amdgcn_perm(bfbits(b), bfbits(a), 0x07060302u);
}

__device__ __forceinline__ void gload_lds16(const void* g, void* l) {
    __builtin_amdgcn_global_load_lds(
        (const __attribute__((address_space(1))) unsigned int*)g,
        (__attribute__((address_space(3))) unsigned int*)l, 16, 0, 0);
}

// ------------------------------------------- prep: weights->bf16 + GN stats
__global__ __launch_bounds__(256) void prep(const float* __restrict__ wq,
                                            const float* __restrict__ wk,
                                            const float* __restrict__ wv,
                                            const float* __restrict__ wp,
                                            unsigned short* __restrict__ oq,
                                            unsigned short* __restrict__ ok,
                                            unsigned short* __restrict__ ov,
                                            unsigned short* __restrict__ op,
                                            const float* __restrict__ x,
                                            float* __restrict__ acc) {
    int bid = blockIdx.x;
    if (bid < 256) {
        int idx = bid * 1024 + threadIdx.x * 4;
        int which = idx >> 16, i = idx & 65535;
        const float* src = (which == 0) ? wq : (which == 1) ? wk : (which == 2) ? wv : wp;
        unsigned short* dst = (which == 0) ? oq : (which == 1) ? ok : (which == 2) ? ov : op;
        // fold softmax scale 512^-0.5 AND log2(e) into wq (softmax uses exp2)
        float scl = (which == 0) ? (0.044194173824159216f * 1.4426950408889634f) : 1.0f;
        float4 v = *(const float4*)(src + i);
        ushort4 o;
        o.x = f2bf(v.x * scl); o.y = f2bf(v.y * scl);
        o.z = f2bf(v.z * scl); o.w = f2bf(v.w * scl);
        *(ushort4*)(dst + i) = o;
    } else {
        int bid2 = bid - 256;                  // [0,512)
        int bg = bid2 >> 3, ch = bid2 & 7;
        const float4* xp = (const float4*)(x + (size_t)bg * 65536 + ch * 8192);
        float s = 0.f, s2 = 0.f;
#pragma unroll
        for (int i = 0; i < 8; i++) {
            float4 v = xp[threadIdx.x + i * 256];
            s  += v.x + v.y + v.z + v.w;
            s2 += v.x * v.x + v.y * v.y + v.z * v.z + v.w * v.w;
        }
        for (int m = 1; m < 64; m <<= 1) { s += __shfl_xor(s, m); s2 += __shfl_xor(s2, m); }
        __shared__ float ls[8];
        int w = threadIdx.x >> 6, lane = threadIdx.x & 63;
        if (lane == 0) { ls[w] = s; ls[4 + w] = s2; }
        __syncthreads();
        if (threadIdx.x == 0) {
            acc[bg * 16 + ch * 2]     = ls[0] + ls[1] + ls[2] + ls[3];
            acc[bg * 16 + ch * 2 + 1] = ls[4] + ls[5] + ls[6] + ls[7];
        }
    }
}

// --------------------------------------------------- QKV GEMM fused with GN
__global__ __launch_bounds__(256) void qkv_fused(const float* __restrict__ x,
                                                 const float* __restrict__ acc,
                                                 const float* __restrict__ gnw,
                                                 const float* __restrict__ gnb,
                                                 const unsigned short* __restrict__ wqb,
                                                 const unsigned short* __restrict__ wkb,
                                                 const unsigned short* __restrict__ wvb,
                                                 unsigned short* __restrict__ qt,
                                                 unsigned short* __restrict__ kt,
                                                 unsigned short* __restrict__ vv) {
    int b = blockIdx.z, half = blockIdx.y, nx = blockIdx.x;
    int n0 = nx * 64;
    int t = threadIdx.x, w = t >> 6, lane = t & 63, quad = lane >> 4, c4 = lane & 15;
    __shared__ __align__(16) unsigned short xl[17408];   // p1: [64][264]; p2: Q-et@0, K-et@8704 ([64][136])
    __shared__ __align__(16) unsigned short ebuf[9216];  // V-et2 [128][72]
    __shared__ float gs[8];
    if (t < 4) {
        float s0 = 0.f, s1 = 0.f;
#pragma unroll
        for (int p = 0; p < 8; p++) {
            s0 += acc[(b * 4 + t) * 16 + p * 2];
            s1 += acc[(b * 4 + t) * 16 + p * 2 + 1];
        }
        float mean = s0 * (1.f / 65536.f);
        float var = s1 * (1.f / 65536.f) - mean * mean;
        gs[2 * t] = mean;
        gs[2 * t + 1] = rsqrtf(var + 1e-5f);
    }
    __syncthreads();
    // ---- load + normalize x-tile -> xl [n 64][c pitch 264]
    {
        int col = t & 15, crow = t >> 4;
#pragma unroll
        for (int p = 0; p < 16; p++) {
            int c = p * 16 + crow;
            int g = c >> 6;
            float sc = gs[g * 2 + 1] * gnw[c];
            float bs = gnb[c] - gs[g * 2] * sc;
            float4 v = *(const float4*)(x + ((size_t)b * 256 + c) * 1024 + n0 + col * 4);
            int nl = col * 4;
            xl[(nl + 0) * 264 + c] = (unsigned short)(bfbits(fmaf(v.x, sc, bs)) >> 16);
            xl[(nl + 1) * 264 + c] = (unsigned short)(bfbits(fmaf(v.y, sc, bs)) >> 16);
            xl[(nl + 2) * 264 + c] = (unsigned short)(bfbits(fmaf(v.z, sc, bs)) >> 16);
            xl[(nl + 3) * 264 + c] = (unsigned short)(bfbits(fmaf(v.w, sc, bs)) >> 16);
        }
    }
    __syncthreads();
    int wm = (w >> 1) * 64, wn = (w & 1) * 32;
    int mbase = half * 128 + wm;
    int bh = b * 2 + half;
    f32x4 aq[4][2] = {}, akk[4][2] = {}, av[4][2] = {};
#pragma unroll
    for (int k = 0; k < 256; k += 32) {
        bf16x8 bfr[2];
#pragma unroll
        for (int i = 0; i < 2; i++)
            bfr[i] = *(const bf16x8*)&xl[(wn + i * 16 + c4) * 264 + k + quad * 8];
#pragma unroll
        for (int mi = 0; mi < 4; mi++) {
            bf16x8 afq = *(const bf16x8*)(wqb + (mbase + mi * 16 + c4) * 256 + k + quad * 8);
            bf16x8 afk = *(const bf16x8*)(wkb + (mbase + mi * 16 + c4) * 256 + k + quad * 8);
            bf16x8 afv = *(const bf16x8*)(wvb + (mbase + mi * 16 + c4) * 256 + k + quad * 8);
#pragma unroll
            for (int ni = 0; ni < 2; ni++) {
                aq[mi][ni]  = __builtin_amdgcn_mfma_f32_16x16x32_bf16(afq, bfr[ni], aq[mi][ni], 0, 0, 0);
                akk[mi][ni] = __builtin_amdgcn_mfma_f32_16x16x32_bf16(afk, bfr[ni], akk[mi][ni], 0, 0, 0);
                av[mi][ni]  = __builtin_amdgcn_mfma_f32_16x16x32_bf16(afv, bfr[ni], av[mi][ni], 0, 0, 0);
            }
        }
    }
    __syncthreads();   // xl reads done; reuse xl + ebuf for epilogue
#pragma unroll
    for (int mi = 0; mi < 4; mi++)
#pragma unroll
        for (int ni = 0; ni < 2; ni++) {
            int row = wn + ni * 16 + c4;          // i-local
            int col = wm + mi * 16 + quad * 4;    // ch
            uint2 uq, uk;
            uq.x = packbf(aq[mi][ni][0], aq[mi][ni][1]);
            uq.y = packbf(aq[mi][ni][2], aq[mi][ni][3]);
            uk.x = packbf(akk[mi][ni][0], akk[mi][ni][1]);
            uk.y = packbf(akk[mi][ni][2], akk[mi][ni][3]);
            *(uint2*)&xl[row * 136 + col] = uq;
            *(uint2*)&xl[8704 + row * 136 + col] = uk;
#pragma unroll
            for (int r = 0; r < 4; r++)
                ebuf[(col + r) * 72 + row] = f2bf(av[mi][ni][r]);
        }
    __syncthreads();
#pragma unroll
    for (int p = 0; p < 4; p++) {
        int i = p * 16 + (t >> 4), off = (t & 15) * 8;
        *(bf16x8*)(qt + ((size_t)bh * 1024 + n0 + i) * 128 + off) =
            *(const bf16x8*)&xl[i * 136 + off];
        *(bf16x8*)(kt + ((size_t)bh * 1024 + n0 + i) * 128 + off) =
            *(const bf16x8*)&xl[8704 + i * 136 + off];
    }
#pragma unroll
    for (int p = 0; p < 4; p++) {
        int ch = p * 32 + (t >> 3), off = (t & 7) * 8;
        *(bf16x8*)(vv + ((size_t)bh * 128 + ch) * 1024 + n0 + off) =
            *(const bf16x8*)&ebuf[ch * 72 + off];
    }
}

// ---------------------- flash attention (R6 exact) + fused partial proj
// grid 512 (R6 attn mapping), 256 thr, 64KB LDS -> 2 blocks/CU, all CUs.
// After flash: O-tile (64 i x 128 c bf16, pitch 136) into LDS; each wave
// GEMMs 64 output channels x 64 rows over its head's K=128; fp32 partials
// atomicAdd'ed into out (h==0 also adds residual x). out is zero-filled by
// the harness before each launch; 2 commutative adds/elem = deterministic.
__global__ __launch_bounds__(256) void attn_proj2(const unsigned short* __restrict__ qt,
                                                  const unsigned short* __restrict__ kt,
                                                  const unsigned short* __restrict__ vv,
                                                  const unsigned short* __restrict__ wpb,
                                                  const float* __restrict__ x,
                                                  float* __restrict__ out) {
    int L = blockIdx.x;
    int xcd = L & 7, jj = L >> 3;
    int bh = (jj >> 4) * 8 + xcd;       // 4 bh per XCD
    int qb = jj & 15;
    int b = bh >> 1, h = bh & 1;
    int tid = threadIdx.x, w = tid >> 6, lane = tid & 63;
    int quad = lane >> 4, c4 = lane & 15;
    __shared__ __align__(16) unsigned short smem[32768];   // 64 KiB
    // klds[buf][idx] = smem[buf*8192 + idx]; vlds[buf][idx] = smem[16384 + buf*8192 + idx]

    const unsigned short* qp = qt + (size_t)bh * 1024 * 128;
    const unsigned short* kp = kt + (size_t)bh * 1024 * 128;
    const unsigned short* vp = vv + (size_t)bh * 128 * 1024;
    int i0 = qb * 64 + w * 16;

    // Q B-frags (16 rows) kept in regs: i = i0 + c4, k = kk*32 + quad*8
    bf16x8 bq[4];
#pragma unroll
    for (int kk = 0; kk < 4; kk++)
        bq[kk] = *(const bf16x8*)(qp + (size_t)(i0 + c4) * 128 + kk * 32 + quad * 8);

    float lsum = 0.f;        // row i = i0 + c4 partial (dup x4 quads)
    f32x4 oacc[8] = {};      // O[i = quad*4+r][c = n*16 + c4]

    // ---- prefetch tile 0 into buffer 0
#pragma unroll
    for (int t = 0; t < 8; t++) {
        int chunk = w * 8 + t;
        if (chunk < 16) {
            int np = chunk >> 2, kk = chunk & 3;
            gload_lds16(kp + (size_t)(np * 16 + c4) * 128 + kk * 32 + quad * 8,
                        &smem[chunk * 512]);
        } else {
            int cc = chunk - 16, n = cc >> 1, kw = cc & 1;
            gload_lds16(vp + (size_t)(n * 16 + c4) * 1024 + kw * 32 + quad * 8,
                        &smem[16384 + cc * 512]);
        }
    }

    for (int jt = 0; jt < 16; jt++) {
        int cur = jt & 1;
        __syncthreads();   // staging of cur visible; prev reads of next-buf done
        // ---- issue prefetch for jt+1 (drained at NEXT barrier, after compute)
        if (jt < 15) {
            int j0n = (jt + 1) * 64, nb = cur ^ 1;
#pragma unroll
            for (int t = 0; t < 8; t++) {
                int chunk = w * 8 + t;
                if (chunk < 16) {
                    int np = chunk >> 2, kk = chunk & 3;
                    gload_lds16(kp + (size_t)(j0n + np * 16 + c4) * 128 + kk * 32 + quad * 8,
                                &smem[nb * 8192 + chunk * 512]);
                } else {
                    int cc = chunk - 16, n = cc >> 1, kw = cc & 1;
                    gload_lds16(vp + (size_t)(n * 16 + c4) * 1024 + j0n + kw * 32 + quad * 8,
                                &smem[16384 + nb * 8192 + cc * 512]);
                }
            }
        }

        // ---- S^T: st[np], j = jt*64 + np*16 + quad*4 + r, i = i0 + c4
        f32x4 st[4] = {};
#pragma unroll
        for (int np = 0; np < 4; np++)
#pragma unroll
            for (int kk = 0; kk < 4; kk++) {
                bf16x8 ak = *(const bf16x8*)&smem[cur * 8192 + (np * 4 + kk) * 512 + lane * 8];
                st[np] = __builtin_amdgcn_mfma_f32_16x16x32_bf16(ak, bq[kk], st[np], 0, 0, 0);
            }

        // ---- p = exp2(s) (log2e folded into wq); accumulate row sums
#pragma unroll
        for (int np = 0; np < 4; np++)
#pragma unroll
            for (int r = 0; r < 4; r++) {
                float p = exp2f(st[np][r]);
                st[np][r] = p;
                lsum += p;
            }

        // ---- pack np pairs; re-frag via shfl (dest-side half select)
        unsigned pk2[2][4];
#pragma unroll
        for (int kw = 0; kw < 2; kw++)
#pragma unroll
            for (int r = 0; r < 4; r++)
                pk2[kw][r] = packbf(st[kw * 2][r], st[kw * 2 + 1][r]);

        int sbase = ((lane & 16) ? 32 : 0) + c4;
        bool hi = (lane & 32) != 0;
#pragma unroll
        for (int kw = 0; kw < 2; kw++) {
            bf16x8 pa;
#pragma unroll
            for (int t = 0; t < 4; t++) {
                unsigned u  = (unsigned)__shfl((int)pk2[kw][t], sbase);
                unsigned u2 = (unsigned)__shfl((int)pk2[kw][t], sbase + 16);
                pa[t]     = (short)(hi ? (u >> 16)  : (u & 0xffffu));
                pa[4 + t] = (short)(hi ? (u2 >> 16) : (u2 & 0xffffu));
            }
#pragma unroll
            for (int n = 0; n < 8; n++) {
                bf16x8 bv = *(const bf16x8*)&smem[16384 + cur * 8192 + (n * 2 + kw) * 512 + lane * 8];
                oacc[n] = __builtin_amdgcn_mfma_f32_16x16x32_bf16(pa, bv, oacc[n], 0, 0, 0);
            }
        }
    }

    // ---- finish row sums (reduce over quads)
    lsum += __shfl_xor(lsum, 16);
    lsum += __shfl_xor(lsum, 32);
    float inv = 1.0f / lsum;
    float ir[4];
#pragma unroll
    for (int r = 0; r < 4; r++) ir[r] = __shfl(inv, quad * 4 + r);

    __syncthreads();   // all K/V LDS reads done -> reuse smem as O-tile
    // ---- O tile [64 i][pitch 136] bf16, c-local = n*16+c4 (head channels)
#pragma unroll
    for (int n = 0; n < 8; n++)
#pragma unroll
        for (int r = 0; r < 4; r++) {
            int il = w * 16 + quad * 4 + r;
            smem[il * 136 + n * 16 + c4] = f2bf(oacc[n][r] * ir[r]);
        }
    __syncthreads();

    // ---- partial proj: wave w owns output channels [w*64, w*64+64),
    //      K = this head's 128 channels of wp (col offset h*128)
    int mbase = w * 64;
    f32x4 pacc[4][4] = {};
#pragma unroll
    for (int k = 0; k < 128; k += 32) {
        bf16x8 af[4], bfr[4];
#pragma unroll
        for (int mi = 0; mi < 4; mi++)
            af[mi] = *(const bf16x8*)(wpb + (size_t)(mbase + mi * 16 + c4) * 256 + h * 128 + k + quad * 8);
#pragma unroll
        for (int ni = 0; ni < 4; ni++)
            bfr[ni] = *(const bf16x8*)&smem[(ni * 16 + c4) * 136 + k + quad * 8];
#pragma unroll
        for (int mi = 0; mi < 4; mi++)
#pragma unroll
            for (int ni = 0; ni < 4; ni++)
                pacc[mi][ni] = __builtin_amdgcn_mfma_f32_16x16x32_bf16(
                    af[mi], bfr[ni], pacc[mi][ni], 0, 0, 0);
    }
    // ---- atomic accumulate into out (h==0 adds residual)
#pragma unroll
    for (int mi = 0; mi < 4; mi++)
#pragma unroll
        for (int ni = 0; ni < 4; ni++)
#pragma unroll
            for (int r = 0; r < 4; r++) {
                int o = mbase + mi * 16 + quad * 4 + r;
                int i = qb * 64 + ni * 16 + c4;
                size_t idx = ((size_t)b * 256 + o) * 1024 + i;
                float val = pacc[mi][ni][r];
                if (h == 0) val += x[idx];
                unsafeAtomicAdd(&out[idx], val);
            }
}

// ---------------------------------------------------------------------------
extern "C" void kernel_launch(void* const* d_in, const int* in_sizes, int n_in,
                              void* d_out, int out_size, void* d_ws, size_t ws_size,
                              hipStream_t stream) {
    const float* x   = (const float*)d_in[0];
    const float* gnw = (const float*)d_in[1];
    const float* gnb = (const float*)d_in[2];
    const float* wq  = (const float*)d_in[3];
    const float* wk  = (const float*)d_in[4];
    const float* wv  = (const float*)d_in[5];
    const float* wp  = (const float*)d_in[6];
    float* out = (float*)d_out;

    char* ws = (char*)d_ws;
    float* acc = (float*)ws;                                        //   4 KiB
    unsigned short* wqb = (unsigned short*)(ws + 4096);             // 128 KiB each
    unsigned short* wkb = (unsigned short*)(ws + 4096 + 131072);
    unsigned short* wvb = (unsigned short*)(ws + 4096 + 2 * 131072);
    unsigned short* wpb = (unsigned short*)(ws + 4096 + 3 * 131072);
    size_t base = 4096 + 4 * 131072;
    const size_t SZ = (size_t)16 * 1024 * 256 * 2;  // 8 MiB each
    unsigned short* qt = (unsigned short*)(ws + base);
    unsigned short* kt = (unsigned short*)(ws + base + SZ);
    unsigned short* vv = (unsigned short*)(ws + base + 2 * SZ);

    prep<<<768, 256, 0, stream>>>(wq, wk, wv, wp, wqb, wkb, wvb, wpb, x, acc);
    qkv_fused<<<dim3(16, 2, 16), 256, 0, stream>>>(x, acc, gnw, gnb,
                                                   wqb, wkb, wvb, qt, kt, vv);
    attn_proj2<<<512, 256, 0, stream>>>(qt, kt, vv, wpb, x, out);
}

// Round 8
// 165.268 us; speedup vs baseline: 3.3107x; 1.1127x over previous
//
#include <hip/hip_runtime.h>
#include <math.h>

// ---------------------------------------------------------------------------
// AttentionBlock: GN(4,256) -> QKV 1x1 conv -> 2-head attn (N=1024, hd=128)
// -> proj -> +residual.  B=16, C=256, H=W=32 (N=1024), fp32 in/out.
// R11: R6 4-kernel structure (prep/qkv/attn/proj; atomics of R10 reverted —
// 8.4M fp32 atomics cost ~17us). attn KVBLK 64->32: LDS 64KB->32KB -> 4
// blocks/CU (16 waves/CU vs 8), barrier drains overlap across co-resident
// blocks. R10 counters: MfmaUtil 10%, Occ 17.7%, stall-dominated -> this
// targets occupancy. All index math inherited from verified R6 template.
// ---------------------------------------------------------------------------

typedef __attribute__((ext_vector_type(8))) short bf16x8;   // 8 bf16 = 4 VGPRs
typedef __attribute__((ext_vector_type(4))) float f32x4;

__device__ __forceinline__ unsigned short f2bf(float f) {   // RNE-ish
    union { float f; unsigned u; } v; v.f = f;
    return (unsigned short)((v.u + 0x7FFFu + ((v.u >> 16) & 1u)) >> 16);
}
__device__ __forceinline__ unsigned bfbits(float f) {       // +half (round up)
    union { float f; unsigned u; } v; v.f = f;
    return v.u + 0x8000u;
}
// pack two floats -> (bf(a) | bf(b)<<16) in 3 VALU ops
__device__ __forceinline__ unsigned packbf(float a, float b) {
    return __builtin_amdgcn_perm(bfbits(b), bfbits(a), 0x07060302u);
}

__device__ __forceinline__ void gload_lds16(const void* g, void* l) {
    __builtin_amdgcn_global_load_lds(
        (const __attribute__((address_space(1))) unsigned int*)g,
        (__attribute__((address_space(3))) unsigned int*)l, 16, 0, 0);
}

// ------------------------------------------- prep: weights->bf16 + GN stats
__global__ __launch_bounds__(256) void prep(const float* __restrict__ wq,
                                            const float* __restrict__ wk,
                                            const float* __restrict__ wv,
                                            const float* __restrict__ wp,
                                            unsigned short* __restrict__ oq,
                                            unsigned short* __restrict__ ok,
                                            unsigned short* __restrict__ ov,
                                            unsigned short* __restrict__ op,
                                            const float* __restrict__ x,
                                            float* __restrict__ acc) {
    int bid = blockIdx.x;
    if (bid < 256) {
        int idx = bid * 1024 + threadIdx.x * 4;
        int which = idx >> 16, i = idx & 65535;
        const float* src = (which == 0) ? wq : (which == 1) ? wk : (which == 2) ? wv : wp;
        unsigned short* dst = (which == 0) ? oq : (which == 1) ? ok : (which == 2) ? ov : op;
        // fold softmax scale 512^-0.5 AND log2(e) into wq (softmax uses exp2)
        float scl = (which == 0) ? (0.044194173824159216f * 1.4426950408889634f) : 1.0f;
        float4 v = *(const float4*)(src + i);
        ushort4 o;
        o.x = f2bf(v.x * scl); o.y = f2bf(v.y * scl);
        o.z = f2bf(v.z * scl); o.w = f2bf(v.w * scl);
        *(ushort4*)(dst + i) = o;
    } else {
        int bid2 = bid - 256;                  // [0,512)
        int bg = bid2 >> 3, ch = bid2 & 7;
        const float4* xp = (const float4*)(x + (size_t)bg * 65536 + ch * 8192);
        float s = 0.f, s2 = 0.f;
#pragma unroll
        for (int i = 0; i < 8; i++) {
            float4 v = xp[threadIdx.x + i * 256];
            s  += v.x + v.y + v.z + v.w;
            s2 += v.x * v.x + v.y * v.y + v.z * v.z + v.w * v.w;
        }
        for (int m = 1; m < 64; m <<= 1) { s += __shfl_xor(s, m); s2 += __shfl_xor(s2, m); }
        __shared__ float ls[8];
        int w = threadIdx.x >> 6, lane = threadIdx.x & 63;
        if (lane == 0) { ls[w] = s; ls[4 + w] = s2; }
        __syncthreads();
        if (threadIdx.x == 0) {
            acc[bg * 16 + ch * 2]     = ls[0] + ls[1] + ls[2] + ls[3];
            acc[bg * 16 + ch * 2 + 1] = ls[4] + ls[5] + ls[6] + ls[7];
        }
    }
}

// --------------------------------------------------- QKV GEMM fused with GN
__global__ __launch_bounds__(256) void qkv_fused(const float* __restrict__ x,
                                                 const float* __restrict__ acc,
                                                 const float* __restrict__ gnw,
                                                 const float* __restrict__ gnb,
                                                 const unsigned short* __restrict__ wqb,
                                                 const unsigned short* __restrict__ wkb,
                                                 const unsigned short* __restrict__ wvb,
                                                 unsigned short* __restrict__ qt,
                                                 unsigned short* __restrict__ kt,
                                                 unsigned short* __restrict__ vv) {
    int b = blockIdx.z, half = blockIdx.y, nx = blockIdx.x;
    int n0 = nx * 64;
    int t = threadIdx.x, w = t >> 6, lane = t & 63, quad = lane >> 4, c4 = lane & 15;
    __shared__ __align__(16) unsigned short xl[17408];   // p1: [64][264]; p2: Q-et@0, K-et@8704 ([64][136])
    __shared__ __align__(16) unsigned short ebuf[9216];  // V-et2 [128][72]
    __shared__ float gs[8];
    if (t < 4) {
        float s0 = 0.f, s1 = 0.f;
#pragma unroll
        for (int p = 0; p < 8; p++) {
            s0 += acc[(b * 4 + t) * 16 + p * 2];
            s1 += acc[(b * 4 + t) * 16 + p * 2 + 1];
        }
        float mean = s0 * (1.f / 65536.f);
        float var = s1 * (1.f / 65536.f) - mean * mean;
        gs[2 * t] = mean;
        gs[2 * t + 1] = rsqrtf(var + 1e-5f);
    }
    __syncthreads();
    // ---- load + normalize x-tile -> xl [n 64][c pitch 264]
    {
        int col = t & 15, crow = t >> 4;
#pragma unroll
        for (int p = 0; p < 16; p++) {
            int c = p * 16 + crow;
            int g = c >> 6;
            float sc = gs[g * 2 + 1] * gnw[c];
            float bs = gnb[c] - gs[g * 2] * sc;
            float4 v = *(const float4*)(x + ((size_t)b * 256 + c) * 1024 + n0 + col * 4);
            int nl = col * 4;
            xl[(nl + 0) * 264 + c] = (unsigned short)(bfbits(fmaf(v.x, sc, bs)) >> 16);
            xl[(nl + 1) * 264 + c] = (unsigned short)(bfbits(fmaf(v.y, sc, bs)) >> 16);
            xl[(nl + 2) * 264 + c] = (unsigned short)(bfbits(fmaf(v.z, sc, bs)) >> 16);
            xl[(nl + 3) * 264 + c] = (unsigned short)(bfbits(fmaf(v.w, sc, bs)) >> 16);
        }
    }
    __syncthreads();
    int wm = (w >> 1) * 64, wn = (w & 1) * 32;
    int mbase = half * 128 + wm;
    int bh = b * 2 + half;
    f32x4 aq[4][2] = {}, akk[4][2] = {}, av[4][2] = {};
#pragma unroll
    for (int k = 0; k < 256; k += 32) {
        bf16x8 bfr[2];
#pragma unroll
        for (int i = 0; i < 2; i++)
            bfr[i] = *(const bf16x8*)&xl[(wn + i * 16 + c4) * 264 + k + quad * 8];
#pragma unroll
        for (int mi = 0; mi < 4; mi++) {
            bf16x8 afq = *(const bf16x8*)(wqb + (mbase + mi * 16 + c4) * 256 + k + quad * 8);
            bf16x8 afk = *(const bf16x8*)(wkb + (mbase + mi * 16 + c4) * 256 + k + quad * 8);
            bf16x8 afv = *(const bf16x8*)(wvb + (mbase + mi * 16 + c4) * 256 + k + quad * 8);
#pragma unroll
            for (int ni = 0; ni < 2; ni++) {
                aq[mi][ni]  = __builtin_amdgcn_mfma_f32_16x16x32_bf16(afq, bfr[ni], aq[mi][ni], 0, 0, 0);
                akk[mi][ni] = __builtin_amdgcn_mfma_f32_16x16x32_bf16(afk, bfr[ni], akk[mi][ni], 0, 0, 0);
                av[mi][ni]  = __builtin_amdgcn_mfma_f32_16x16x32_bf16(afv, bfr[ni], av[mi][ni], 0, 0, 0);
            }
        }
    }
    __syncthreads();   // xl reads done; reuse xl + ebuf for epilogue
#pragma unroll
    for (int mi = 0; mi < 4; mi++)
#pragma unroll
        for (int ni = 0; ni < 2; ni++) {
            int row = wn + ni * 16 + c4;          // i-local
            int col = wm + mi * 16 + quad * 4;    // ch
            uint2 uq, uk;
            uq.x = packbf(aq[mi][ni][0], aq[mi][ni][1]);
            uq.y = packbf(aq[mi][ni][2], aq[mi][ni][3]);
            uk.x = packbf(akk[mi][ni][0], akk[mi][ni][1]);
            uk.y = packbf(akk[mi][ni][2], akk[mi][ni][3]);
            *(uint2*)&xl[row * 136 + col] = uq;
            *(uint2*)&xl[8704 + row * 136 + col] = uk;
#pragma unroll
            for (int r = 0; r < 4; r++)
                ebuf[(col + r) * 72 + row] = f2bf(av[mi][ni][r]);
        }
    __syncthreads();
#pragma unroll
    for (int p = 0; p < 4; p++) {
        int i = p * 16 + (t >> 4), off = (t & 15) * 8;
        *(bf16x8*)(qt + ((size_t)bh * 1024 + n0 + i) * 128 + off) =
            *(const bf16x8*)&xl[i * 136 + off];
        *(bf16x8*)(kt + ((size_t)bh * 1024 + n0 + i) * 128 + off) =
            *(const bf16x8*)&xl[8704 + i * 136 + off];
    }
#pragma unroll
    for (int p = 0; p < 4; p++) {
        int ch = p * 32 + (t >> 3), off = (t & 7) * 8;
        *(bf16x8*)(vv + ((size_t)bh * 128 + ch) * 1024 + n0 + off) =
            *(const bf16x8*)&ebuf[ch * 72 + off];
    }
}

// ---------------------------- flash attention, KVBLK=32 (4 blocks/CU)
// grid 512 XCD-swizzled (R6 mapping). LDS: K dbuf 2x8KB + V dbuf 2x8KB =
// 32KB -> 4 blocks/CU, 16 waves/CU. 32 j-tiles of 32; per tile: 8 S^T MFMA
// + 8 PV MFMA per wave; staging 16 chunks (4/wave) via global_load_lds.
__global__ __launch_bounds__(256) void attn_kernel(const unsigned short* __restrict__ qt,
                                                   const unsigned short* __restrict__ kt,
                                                   const unsigned short* __restrict__ vv,
                                                   unsigned short* __restrict__ ot) {
    int L = blockIdx.x;
    int xcd = L & 7, jj = L >> 3;
    int bh = (jj >> 4) * 8 + xcd;       // 4 bh per XCD
    int qb = jj & 15;
    int b = bh >> 1, h = bh & 1;
    int tid = threadIdx.x, w = tid >> 6, lane = tid & 63;
    int quad = lane >> 4, c4 = lane & 15;
    __shared__ __align__(16) unsigned short klds[2][4096];   // 2 x 8 KB (32j x 128k)
    __shared__ __align__(16) unsigned short vlds[2][4096];   // 2 x 8 KB (128c x 32j)

    const unsigned short* qp = qt + (size_t)bh * 1024 * 128;
    const unsigned short* kp = kt + (size_t)bh * 1024 * 128;
    const unsigned short* vp = vv + (size_t)bh * 128 * 1024;
    int i0 = qb * 64 + w * 16;

    // Q B-frags (16 rows) kept in regs: i = i0 + c4, k = kk*32 + quad*8
    bf16x8 bq[4];
#pragma unroll
    for (int kk = 0; kk < 4; kk++)
        bq[kk] = *(const bf16x8*)(qp + (size_t)(i0 + c4) * 128 + kk * 32 + quad * 8);

    float lsum = 0.f;        // row i = i0 + c4 partial (dup x4 quads)
    f32x4 oacc[8] = {};      // O[i = quad*4+r][c = n*16 + c4]

    // ---- prefetch tile 0 into buffer 0: 16 chunks of 512 shorts, 4/wave
    // K chunk np*4+kk (np<2): rows np*16+c4, cols kk*32+quad*8
    // V chunk 8+n (n<8):      rows n*16+c4 (c), cols j-local quad*8
#pragma unroll
    for (int t = 0; t < 4; t++) {
        int chunk = w * 4 + t;
        if (chunk < 8) {
            int np = chunk >> 2, kk = chunk & 3;
            gload_lds16(kp + (size_t)(np * 16 + c4) * 128 + kk * 32 + quad * 8,
                        &klds[0][chunk * 512]);
        } else {
            int n = chunk - 8;
            gload_lds16(vp + (size_t)(n * 16 + c4) * 1024 + quad * 8,
                        &vlds[0][n * 512]);
        }
    }

    for (int jt = 0; jt < 32; jt++) {
        int cur = jt & 1;
        __syncthreads();   // staging of cur visible; prev reads of next-buf done
        // ---- issue prefetch for jt+1 (drained at NEXT barrier, after compute)
        if (jt < 31) {
            int j0n = (jt + 1) * 32, nb = cur ^ 1;
#pragma unroll
            for (int t = 0; t < 4; t++) {
                int chunk = w * 4 + t;
                if (chunk < 8) {
                    int np = chunk >> 2, kk = chunk & 3;
                    gload_lds16(kp + (size_t)(j0n + np * 16 + c4) * 128 + kk * 32 + quad * 8,
                                &klds[nb][chunk * 512]);
                } else {
                    int n = chunk - 8;
                    gload_lds16(vp + (size_t)(n * 16 + c4) * 1024 + j0n + quad * 8,
                                &vlds[nb][n * 512]);
                }
            }
        }

        // ---- S^T: st[np], j = jt*32 + np*16 + quad*4 + r, i = i0 + c4
        f32x4 st[2] = {};
#pragma unroll
        for (int np = 0; np < 2; np++)
#pragma unroll
            for (int kk = 0; kk < 4; kk++) {
                bf16x8 ak = *(const bf16x8*)&klds[cur][(np * 4 + kk) * 512 + lane * 8];
                st[np] = __builtin_amdgcn_mfma_f32_16x16x32_bf16(ak, bq[kk], st[np], 0, 0, 0);
            }

        // ---- p = exp2(s) (log2e folded into wq); accumulate row sums
#pragma unroll
        for (int np = 0; np < 2; np++)
#pragma unroll
            for (int r = 0; r < 4; r++) {
                float p = exp2f(st[np][r]);
                st[np][r] = p;
                lsum += p;
            }

        // ---- pack np pair; re-frag via shfl (dest-side half select)
        unsigned pk2[4];
#pragma unroll
        for (int r = 0; r < 4; r++)
            pk2[r] = packbf(st[0][r], st[1][r]);

        int sbase = ((lane & 16) ? 32 : 0) + c4;
        bool hi = (lane & 32) != 0;
        bf16x8 pa;
#pragma unroll
        for (int t = 0; t < 4; t++) {
            unsigned u  = (unsigned)__shfl((int)pk2[t], sbase);
            unsigned u2 = (unsigned)__shfl((int)pk2[t], sbase + 16);
            pa[t]     = (short)(hi ? (u >> 16)  : (u & 0xffffu));
            pa[4 + t] = (short)(hi ? (u2 >> 16) : (u2 & 0xffffu));
        }
#pragma unroll
        for (int n = 0; n < 8; n++) {
            bf16x8 bv = *(const bf16x8*)&vlds[cur][n * 512 + lane * 8];
            oacc[n] = __builtin_amdgcn_mfma_f32_16x16x32_bf16(pa, bv, oacc[n], 0, 0, 0);
        }
    }

    // ---- finish row sums (reduce over quads), epilogue
    lsum += __shfl_xor(lsum, 16);
    lsum += __shfl_xor(lsum, 32);
    float inv = 1.0f / lsum;
    float ir[4];
#pragma unroll
    for (int r = 0; r < 4; r++) ir[r] = __shfl(inv, quad * 4 + r);
#pragma unroll
    for (int n = 0; n < 8; n++)
#pragma unroll
        for (int r = 0; r < 4; r++) {
            int i = i0 + quad * 4 + r;
            int c = h * 128 + n * 16 + c4;
            ot[((size_t)b * 1024 + i) * 256 + c] = f2bf(oacc[n][r] * ir[r]);
        }
}

// ------------------------------------------------------ proj + residual
__global__ __launch_bounds__(256) void proj_gemm(const unsigned short* __restrict__ wpb,
                                                 const unsigned short* __restrict__ ot,
                                                 const float* __restrict__ x,
                                                 float* __restrict__ out) {
    int b = blockIdx.z;
    int my = blockIdx.y;   // 0..1
    int nx = blockIdx.x;   // 0..15
    int tid = threadIdx.x;
    int w = tid >> 6, lane = tid & 63, quad = lane >> 4, c4 = lane & 15;
    int wm = (w >> 1) * 64, wn = (w & 1) * 32;
    int mbase = my * 128 + wm;
    int nbase = nx * 64 + wn;
    const unsigned short* ob = ot + (size_t)b * 1024 * 256;

    f32x4 acc[4][2] = {};
#pragma unroll
    for (int k = 0; k < 256; k += 32) {
        bf16x8 af[4], bfr[2];
#pragma unroll
        for (int i = 0; i < 4; i++)
            af[i] = *(const bf16x8*)(wpb + (mbase + i * 16 + c4) * 256 + k + quad * 8);
#pragma unroll
        for (int i = 0; i < 2; i++)
            bfr[i] = *(const bf16x8*)(ob + (size_t)(nbase + i * 16 + c4) * 256 + k + quad * 8);
#pragma unroll
        for (int mi = 0; mi < 4; mi++)
#pragma unroll
            for (int ni = 0; ni < 2; ni++)
                acc[mi][ni] = __builtin_amdgcn_mfma_f32_16x16x32_bf16(
                    af[mi], bfr[ni], acc[mi][ni], 0, 0, 0);
    }
#pragma unroll
    for (int mi = 0; mi < 4; mi++)
#pragma unroll
        for (int ni = 0; ni < 2; ni++)
#pragma unroll
            for (int r = 0; r < 4; r++) {
                int o = mbase + mi * 16 + quad * 4 + r;
                int i = nbase + ni * 16 + c4;
                size_t idx = ((size_t)b * 256 + o) * 1024 + i;
                out[idx] = acc[mi][ni][r] + x[idx];
            }
}

// ---------------------------------------------------------------------------
extern "C" void kernel_launch(void* const* d_in, const int* in_sizes, int n_in,
                              void* d_out, int out_size, void* d_ws, size_t ws_size,
                              hipStream_t stream) {
    const float* x   = (const float*)d_in[0];
    const float* gnw = (const float*)d_in[1];
    const float* gnb = (const float*)d_in[2];
    const float* wq  = (const float*)d_in[3];
    const float* wk  = (const float*)d_in[4];
    const float* wv  = (const float*)d_in[5];
    const float* wp  = (const float*)d_in[6];
    float* out = (float*)d_out;

    char* ws = (char*)d_ws;
    float* acc = (float*)ws;                                        //   4 KiB
    unsigned short* wqb = (unsigned short*)(ws + 4096);             // 128 KiB each
    unsigned short* wkb = (unsigned short*)(ws + 4096 + 131072);
    unsigned short* wvb = (unsigned short*)(ws + 4096 + 2 * 131072);
    unsigned short* wpb = (unsigned short*)(ws + 4096 + 3 * 131072);
    size_t base = 4096 + 4 * 131072;
    const size_t SZ = (size_t)16 * 1024 * 256 * 2;  // 8 MiB each
    unsigned short* qt = (unsigned short*)(ws + base);
    unsigned short* kt = (unsigned short*)(ws + base + SZ);
    unsigned short* vv = (unsigned short*)(ws + base + 2 * SZ);
    unsigned short* ot = (unsigned short*)(ws + base + 3 * SZ);

    prep<<<768, 256, 0, stream>>>(wq, wk, wv, wp, wqb, wkb, wvb, wpb, x, acc);
    qkv_fused<<<dim3(16, 2, 16), 256, 0, stream>>>(x, acc, gnw, gnb,
                                                   wqb, wkb, wvb, qt, kt, vv);
    attn_kernel<<<512, 256, 0, stream>>>(qt, kt, vv, ot);
    proj_gemm<<<dim3(16, 2, 16), 256, 0, stream>>>(wpb, ot, x, out);
}

// Round 9
// 159.559 us; speedup vs baseline: 3.4291x; 1.0358x over previous
//
#include <hip/hip_runtime.h>
#include <math.h>

// ---------------------------------------------------------------------------
// AttentionBlock: GN(4,256) -> QKV 1x1 conv -> 2-head attn (N=1024, hd=128)
// -> proj -> +residual.  B=16, C=256, H=W=32 (N=1024), fp32 in/out.
// R12: prep + qkv verbatim R6. attn_proj3 = R9's both-heads-per-block fusion
// (verified index math) with R9's two mistakes fixed: V STAGED in LDS (not
// global-direct) and KVBLK=32 so K+V dbuf for both heads = 64KB at 512 thr
// -> 2 blocks/CU = 16 waves/CU (same wave pool as R11 attn). Flash per-wave
// math = R11 verbatim (KVBLK=32). O-tile [64][264] + proj + residual = R9
// verbatim. No ot round-trip (saves 32MB traffic + 1 dispatch), no atomics.
// ---------------------------------------------------------------------------

typedef __attribute__((ext_vector_type(8))) short bf16x8;   // 8 bf16 = 4 VGPRs
typedef __attribute__((ext_vector_type(4))) float f32x4;

__device__ __forceinline__ unsigned short f2bf(float f) {   // RNE-ish
    union { float f; unsigned u; } v; v.f = f;
    return (unsigned short)((v.u + 0x7FFFu + ((v.u >> 16) & 1u)) >> 16);
}
__device__ __forceinline__ unsigned bfbits(float f) {       // +half (round up)
    union { float f; unsigned u; } v; v.f = f;
    return v.u + 0x8000u;
}
// pack two floats -> (bf(a) | bf(b)<<16) in 3 VALU ops
__device__ __forceinline__ unsigned packbf(float a, float b) {
    return __builtin_amdgcn_perm(bfbits(b), bfbits(a), 0x07060302u);
}

__device__ __forceinline__ void gload_lds16(const void* g, void* l) {
    __builtin_amdgcn_global_load_lds(
        (const __attribute__((address_space(1))) unsigned int*)g,
        (__attribute__((address_space(3))) unsigned int*)l, 16, 0, 0);
}

// ------------------------------------------- prep: weights->bf16 + GN stats
__global__ __launch_bounds__(256) void prep(const float* __restrict__ wq,
                                            const float* __restrict__ wk,
                                            const float* __restrict__ wv,
                                            const float* __restrict__ wp,
                                            unsigned short* __restrict__ oq,
                                            unsigned short* __restrict__ ok,
                                            unsigned short* __restrict__ ov,
                                            unsigned short* __restrict__ op,
                                            const float* __restrict__ x,
                                            float* __restrict__ acc) {
    int bid = blockIdx.x;
    if (bid < 256) {
        int idx = bid * 1024 + threadIdx.x * 4;
        int which = idx >> 16, i = idx & 65535;
        const float* src = (which == 0) ? wq : (which == 1) ? wk : (which == 2) ? wv : wp;
        unsigned short* dst = (which == 0) ? oq : (which == 1) ? ok : (which == 2) ? ov : op;
        // fold softmax scale 512^-0.5 AND log2(e) into wq (softmax uses exp2)
        float scl = (which == 0) ? (0.044194173824159216f * 1.4426950408889634f) : 1.0f;
        float4 v = *(const float4*)(src + i);
        ushort4 o;
        o.x = f2bf(v.x * scl); o.y = f2bf(v.y * scl);
        o.z = f2bf(v.z * scl); o.w = f2bf(v.w * scl);
        *(ushort4*)(dst + i) = o;
    } else {
        int bid2 = bid - 256;                  // [0,512)
        int bg = bid2 >> 3, ch = bid2 & 7;
        const float4* xp = (const float4*)(x + (size_t)bg * 65536 + ch * 8192);
        float s = 0.f, s2 = 0.f;
#pragma unroll
        for (int i = 0; i < 8; i++) {
            float4 v = xp[threadIdx.x + i * 256];
            s  += v.x + v.y + v.z + v.w;
            s2 += v.x * v.x + v.y * v.y + v.z * v.z + v.w * v.w;
        }
        for (int m = 1; m < 64; m <<= 1) { s += __shfl_xor(s, m); s2 += __shfl_xor(s2, m); }
        __shared__ float ls[8];
        int w = threadIdx.x >> 6, lane = threadIdx.x & 63;
        if (lane == 0) { ls[w] = s; ls[4 + w] = s2; }
        __syncthreads();
        if (threadIdx.x == 0) {
            acc[bg * 16 + ch * 2]     = ls[0] + ls[1] + ls[2] + ls[3];
            acc[bg * 16 + ch * 2 + 1] = ls[4] + ls[5] + ls[6] + ls[7];
        }
    }
}

// --------------------------------------------------- QKV GEMM fused with GN
__global__ __launch_bounds__(256) void qkv_fused(const float* __restrict__ x,
                                                 const float* __restrict__ acc,
                                                 const float* __restrict__ gnw,
                                                 const float* __restrict__ gnb,
                                                 const unsigned short* __restrict__ wqb,
                                                 const unsigned short* __restrict__ wkb,
                                                 const unsigned short* __restrict__ wvb,
                                                 unsigned short* __restrict__ qt,
                                                 unsigned short* __restrict__ kt,
                                                 unsigned short* __restrict__ vv) {
    int b = blockIdx.z, half = blockIdx.y, nx = blockIdx.x;
    int n0 = nx * 64;
    int t = threadIdx.x, w = t >> 6, lane = t & 63, quad = lane >> 4, c4 = lane & 15;
    __shared__ __align__(16) unsigned short xl[17408];   // p1: [64][264]; p2: Q-et@0, K-et@8704 ([64][136])
    __shared__ __align__(16) unsigned short ebuf[9216];  // V-et2 [128][72]
    __shared__ float gs[8];
    if (t < 4) {
        float s0 = 0.f, s1 = 0.f;
#pragma unroll
        for (int p = 0; p < 8; p++) {
            s0 += acc[(b * 4 + t) * 16 + p * 2];
            s1 += acc[(b * 4 + t) * 16 + p * 2 + 1];
        }
        float mean = s0 * (1.f / 65536.f);
        float var = s1 * (1.f / 65536.f) - mean * mean;
        gs[2 * t] = mean;
        gs[2 * t + 1] = rsqrtf(var + 1e-5f);
    }
    __syncthreads();
    // ---- load + normalize x-tile -> xl [n 64][c pitch 264]
    {
        int col = t & 15, crow = t >> 4;
#pragma unroll
        for (int p = 0; p < 16; p++) {
            int c = p * 16 + crow;
            int g = c >> 6;
            float sc = gs[g * 2 + 1] * gnw[c];
            float bs = gnb[c] - gs[g * 2] * sc;
            float4 v = *(const float4*)(x + ((size_t)b * 256 + c) * 1024 + n0 + col * 4);
            int nl = col * 4;
            xl[(nl + 0) * 264 + c] = (unsigned short)(bfbits(fmaf(v.x, sc, bs)) >> 16);
            xl[(nl + 1) * 264 + c] = (unsigned short)(bfbits(fmaf(v.y, sc, bs)) >> 16);
            xl[(nl + 2) * 264 + c] = (unsigned short)(bfbits(fmaf(v.z, sc, bs)) >> 16);
            xl[(nl + 3) * 264 + c] = (unsigned short)(bfbits(fmaf(v.w, sc, bs)) >> 16);
        }
    }
    __syncthreads();
    int wm = (w >> 1) * 64, wn = (w & 1) * 32;
    int mbase = half * 128 + wm;
    int bh = b * 2 + half;
    f32x4 aq[4][2] = {}, akk[4][2] = {}, av[4][2] = {};
#pragma unroll
    for (int k = 0; k < 256; k += 32) {
        bf16x8 bfr[2];
#pragma unroll
        for (int i = 0; i < 2; i++)
            bfr[i] = *(const bf16x8*)&xl[(wn + i * 16 + c4) * 264 + k + quad * 8];
#pragma unroll
        for (int mi = 0; mi < 4; mi++) {
            bf16x8 afq = *(const bf16x8*)(wqb + (mbase + mi * 16 + c4) * 256 + k + quad * 8);
            bf16x8 afk = *(const bf16x8*)(wkb + (mbase + mi * 16 + c4) * 256 + k + quad * 8);
            bf16x8 afv = *(const bf16x8*)(wvb + (mbase + mi * 16 + c4) * 256 + k + quad * 8);
#pragma unroll
            for (int ni = 0; ni < 2; ni++) {
                aq[mi][ni]  = __builtin_amdgcn_mfma_f32_16x16x32_bf16(afq, bfr[ni], aq[mi][ni], 0, 0, 0);
                akk[mi][ni] = __builtin_amdgcn_mfma_f32_16x16x32_bf16(afk, bfr[ni], akk[mi][ni], 0, 0, 0);
                av[mi][ni]  = __builtin_amdgcn_mfma_f32_16x16x32_bf16(afv, bfr[ni], av[mi][ni], 0, 0, 0);
            }
        }
    }
    __syncthreads();   // xl reads done; reuse xl + ebuf for epilogue
#pragma unroll
    for (int mi = 0; mi < 4; mi++)
#pragma unroll
        for (int ni = 0; ni < 2; ni++) {
            int row = wn + ni * 16 + c4;          // i-local
            int col = wm + mi * 16 + quad * 4;    // ch
            uint2 uq, uk;
            uq.x = packbf(aq[mi][ni][0], aq[mi][ni][1]);
            uq.y = packbf(aq[mi][ni][2], aq[mi][ni][3]);
            uk.x = packbf(akk[mi][ni][0], akk[mi][ni][1]);
            uk.y = packbf(akk[mi][ni][2], akk[mi][ni][3]);
            *(uint2*)&xl[row * 136 + col] = uq;
            *(uint2*)&xl[8704 + row * 136 + col] = uk;
#pragma unroll
            for (int r = 0; r < 4; r++)
                ebuf[(col + r) * 72 + row] = f2bf(av[mi][ni][r]);
        }
    __syncthreads();
#pragma unroll
    for (int p = 0; p < 4; p++) {
        int i = p * 16 + (t >> 4), off = (t & 15) * 8;
        *(bf16x8*)(qt + ((size_t)bh * 1024 + n0 + i) * 128 + off) =
            *(const bf16x8*)&xl[i * 136 + off];
        *(bf16x8*)(kt + ((size_t)bh * 1024 + n0 + i) * 128 + off) =
            *(const bf16x8*)&xl[8704 + i * 136 + off];
    }
#pragma unroll
    for (int p = 0; p < 4; p++) {
        int ch = p * 32 + (t >> 3), off = (t & 7) * 8;
        *(bf16x8*)(vv + ((size_t)bh * 128 + ch) * 1024 + n0 + off) =
            *(const bf16x8*)&ebuf[ch * 72 + off];
    }
}

// ----------------- fused attention (both heads, KVBLK=32) + proj + residual
// grid 256 (R9 mapping: 2 b x 16 qb per XCD), 512 thr = 8 waves; waves 0-3
// head 0 (wl=w&3 owns rows wl*16..+16), waves 4-7 head 1. LDS 64KB:
//   K: smem[buf*8192 + h*4096 + chunk*512]   (buf,h in {0,1}, chunk<8)
//   V: smem[16384 + buf*8192 + h*4096 + n*512]
// After flash: smem reused as O-tile [64][264] bf16 -> proj (R9 verbatim).
__global__ __launch_bounds__(512) void attn_proj3(const unsigned short* __restrict__ qt,
                                                  const unsigned short* __restrict__ kt,
                                                  const unsigned short* __restrict__ vv,
                                                  const unsigned short* __restrict__ wpb,
                                                  const float* __restrict__ x,
                                                  float* __restrict__ out) {
    int L = blockIdx.x;
    int xcd = L & 7, jj = L >> 3;          // jj in [0,32)
    int b = ((jj >> 4) << 3) | xcd;        // batches {xcd, xcd+8} per XCD
    int qb = jj & 15;
    int tid = threadIdx.x, w = tid >> 6, lane = tid & 63;
    int quad = lane >> 4, c4 = lane & 15;
    int h = w >> 2, wl = w & 3;            // head, wave-in-head
    int bh = b * 2 + h;
    __shared__ __align__(16) unsigned short smem[32768];   // 64 KiB exactly

    const unsigned short* qp = qt + (size_t)bh * 131072;
    int i0 = qb * 64 + wl * 16;

    // Q B-frags (16 rows) in regs: i = i0 + c4, k = kk*32 + quad*8
    bf16x8 bq[4];
#pragma unroll
    for (int kk = 0; kk < 4; kk++)
        bq[kk] = *(const bf16x8*)(qp + (size_t)(i0 + c4) * 128 + kk * 32 + quad * 8);

    float lsum = 0.f;        // row i = i0 + c4 partial (dup x4 quads)
    f32x4 oacc[8] = {};      // O[i = quad*4+r][c = n*16 + c4]

    // ---- prefetch tile 0 into buffer 0: 32 chunks of 512 shorts, 4/wave
    // cc<16: K chunk: h2=cc>>3, kc=cc&7 (np=kc>>2, kk=kc&3)
    // cc>=16: V chunk: h2=(cc-16)>>3, n=(cc-16)&7
#pragma unroll
    for (int t = 0; t < 4; t++) {
        int cc = w * 4 + t;
        if (cc < 16) {
            int h2 = cc >> 3, kc = cc & 7;
            int np = kc >> 2, kk = kc & 3;
            const unsigned short* kp2 = kt + (size_t)(b * 2 + h2) * 131072;
            gload_lds16(kp2 + (size_t)(np * 16 + c4) * 128 + kk * 32 + quad * 8,
                        &smem[h2 * 4096 + kc * 512]);
        } else {
            int cc2 = cc - 16, h2 = cc2 >> 3, n = cc2 & 7;
            const unsigned short* vp2 = vv + (size_t)(b * 2 + h2) * 131072;
            gload_lds16(vp2 + (size_t)(n * 16 + c4) * 1024 + quad * 8,
                        &smem[16384 + h2 * 4096 + n * 512]);
        }
    }

    for (int jt = 0; jt < 32; jt++) {
        int cur = jt & 1;
        __syncthreads();   // staging of cur visible; prev reads of next-buf done
        // ---- issue prefetch for jt+1 (drained at NEXT barrier, after compute)
        if (jt < 31) {
            int j0n = (jt + 1) * 32, nb = cur ^ 1;
#pragma unroll
            for (int t = 0; t < 4; t++) {
                int cc = w * 4 + t;
                if (cc < 16) {
                    int h2 = cc >> 3, kc = cc & 7;
                    int np = kc >> 2, kk = kc & 3;
                    const unsigned short* kp2 = kt + (size_t)(b * 2 + h2) * 131072;
                    gload_lds16(kp2 + (size_t)(j0n + np * 16 + c4) * 128 + kk * 32 + quad * 8,
                                &smem[nb * 8192 + h2 * 4096 + kc * 512]);
                } else {
                    int cc2 = cc - 16, h2 = cc2 >> 3, n = cc2 & 7;
                    const unsigned short* vp2 = vv + (size_t)(b * 2 + h2) * 131072;
                    gload_lds16(vp2 + (size_t)(n * 16 + c4) * 1024 + j0n + quad * 8,
                                &smem[16384 + nb * 8192 + h2 * 4096 + n * 512]);
                }
            }
        }

        // ---- S^T: st[np], j = jt*32 + np*16 + quad*4 + r, i = i0 + c4
        f32x4 st[2] = {};
#pragma unroll
        for (int np = 0; np < 2; np++)
#pragma unroll
            for (int kk = 0; kk < 4; kk++) {
                bf16x8 ak = *(const bf16x8*)&smem[cur * 8192 + h * 4096 + (np * 4 + kk) * 512 + lane * 8];
                st[np] = __builtin_amdgcn_mfma_f32_16x16x32_bf16(ak, bq[kk], st[np], 0, 0, 0);
            }

        // ---- p = exp2(s) (log2e folded into wq); accumulate row sums
#pragma unroll
        for (int np = 0; np < 2; np++)
#pragma unroll
            for (int r = 0; r < 4; r++) {
                float p = exp2f(st[np][r]);
                st[np][r] = p;
                lsum += p;
            }

        // ---- pack np pair; re-frag via shfl (dest-side half select)
        unsigned pk2[4];
#pragma unroll
        for (int r = 0; r < 4; r++)
            pk2[r] = packbf(st[0][r], st[1][r]);

        int sbase = ((lane & 16) ? 32 : 0) + c4;
        bool hi = (lane & 32) != 0;
        bf16x8 pa;
#pragma unroll
        for (int t = 0; t < 4; t++) {
            unsigned u  = (unsigned)__shfl((int)pk2[t], sbase);
            unsigned u2 = (unsigned)__shfl((int)pk2[t], sbase + 16);
            pa[t]     = (short)(hi ? (u >> 16)  : (u & 0xffffu));
            pa[4 + t] = (short)(hi ? (u2 >> 16) : (u2 & 0xffffu));
        }
#pragma unroll
        for (int n = 0; n < 8; n++) {
            bf16x8 bv = *(const bf16x8*)&smem[16384 + cur * 8192 + h * 4096 + n * 512 + lane * 8];
            oacc[n] = __builtin_amdgcn_mfma_f32_16x16x32_bf16(pa, bv, oacc[n], 0, 0, 0);
        }
    }

    // ---- finish row sums (reduce over quads)
    lsum += __shfl_xor(lsum, 16);
    lsum += __shfl_xor(lsum, 32);
    float inv = 1.0f / lsum;
    float ir[4];
#pragma unroll
    for (int r = 0; r < 4; r++) ir[r] = __shfl(inv, quad * 4 + r);

    __syncthreads();   // all K/V LDS reads done -> reuse smem as O-tile
    // ---- write O tile [64 rows][264 pitch], c = h*128 + n*16 + c4
#pragma unroll
    for (int n = 0; n < 8; n++)
#pragma unroll
        for (int r = 0; r < 4; r++) {
            int il = wl * 16 + quad * 4 + r;
            int c = h * 128 + n * 16 + c4;
            smem[il * 264 + c] = f2bf(oacc[n][r] * ir[r]);
        }
    __syncthreads();

    // ---- proj + residual: wave w owns output channels [w*32, w*32+32)
    int mbase = w * 32;
    f32x4 pacc[2][4] = {};
#pragma unroll
    for (int k = 0; k < 256; k += 32) {
        bf16x8 af[2], bfr[4];
#pragma unroll
        for (int mi = 0; mi < 2; mi++)
            af[mi] = *(const bf16x8*)(wpb + (size_t)(mbase + mi * 16 + c4) * 256 + k + quad * 8);
#pragma unroll
        for (int ni = 0; ni < 4; ni++)
            bfr[ni] = *(const bf16x8*)&smem[(ni * 16 + c4) * 264 + k + quad * 8];
#pragma unroll
        for (int mi = 0; mi < 2; mi++)
#pragma unroll
            for (int ni = 0; ni < 4; ni++)
                pacc[mi][ni] = __builtin_amdgcn_mfma_f32_16x16x32_bf16(
                    af[mi], bfr[ni], pacc[mi][ni], 0, 0, 0);
    }
#pragma unroll
    for (int mi = 0; mi < 2; mi++)
#pragma unroll
        for (int ni = 0; ni < 4; ni++)
#pragma unroll
            for (int r = 0; r < 4; r++) {
                int o = mbase + mi * 16 + quad * 4 + r;
                int i = qb * 64 + ni * 16 + c4;
                size_t idx = ((size_t)b * 256 + o) * 1024 + i;
                out[idx] = pacc[mi][ni][r] + x[idx];
            }
}

// ---------------------------------------------------------------------------
extern "C" void kernel_launch(void* const* d_in, const int* in_sizes, int n_in,
                              void* d_out, int out_size, void* d_ws, size_t ws_size,
                              hipStream_t stream) {
    const float* x   = (const float*)d_in[0];
    const float* gnw = (const float*)d_in[1];
    const float* gnb = (const float*)d_in[2];
    const float* wq  = (const float*)d_in[3];
    const float* wk  = (const float*)d_in[4];
    const float* wv  = (const float*)d_in[5];
    const float* wp  = (const float*)d_in[6];
    float* out = (float*)d_out;

    char* ws = (char*)d_ws;
    float* acc = (float*)ws;                                        //   4 KiB
    unsigned short* wqb = (unsigned short*)(ws + 4096);             // 128 KiB each
    unsigned short* wkb = (unsigned short*)(ws + 4096 + 131072);
    unsigned short* wvb = (unsigned short*)(ws + 4096 + 2 * 131072);
    unsigned short* wpb = (unsigned short*)(ws + 4096 + 3 * 131072);
    size_t base = 4096 + 4 * 131072;
    const size_t SZ = (size_t)16 * 1024 * 256 * 2;  // 8 MiB each
    unsigned short* qt = (unsigned short*)(ws + base);
    unsigned short* kt = (unsigned short*)(ws + base + SZ);
    unsigned short* vv = (unsigned short*)(ws + base + 2 * SZ);

    prep<<<768, 256, 0, stream>>>(wq, wk, wv, wp, wqb, wkb, wvb, wpb, x, acc);
    qkv_fused<<<dim3(16, 2, 16), 256, 0, stream>>>(x, acc, gnw, gnb,
                                                   wqb, wkb, wvb, qt, kt, vv);
    attn_proj3<<<256, 512, 0, stream>>>(qt, kt, vv, wpb, x, out);
}